// Round 1
// baseline (518.300 us; speedup 1.0000x reference)
//
#include <hip/hip_runtime.h>
#include <hip/hip_bf16.h>
#include <math.h>

#define BB 4
#define SS 512
#define HH 768
#define DD 24
#define MM 96
#define OH 768      // OUT_HID
#define K3H 2304    // 3*H

// workspace layout (floats)
#define OFF_ZJ    0
#define OFF_ZIT   (OFF_ZJ    + BB*SS*DD)      // [b][d][t]
#define OFF_A     (OFF_ZIT   + BB*SS*DD)      // [b][s][m]  (includes s_b1)
#define OFF_BTT   (OFF_A     + BB*SS*MM)      // [b][m][t]
#define OFF_PROBS (OFF_BTT   + BB*SS*MM)      // [b][s][t]
#define OFF_CTX   (OFF_PROBS + BB*SS*SS)      // [b][s][h]
#define OFF_H1    (OFF_CTX   + BB*SS*HH)      // [n][o]
#define OFF_W1T   (OFF_H1    + BB*SS*OH)      // [k][o] 2304x768
#define OFF_W2T   (OFF_W1T   + K3H*OH)        // [k][o] 768x768

// ---------------------------------------------------------------------------
// K1: Z projections + per-row A (Zj·Wa^T + s_b1) and Bt (Zi·Wb^T), transposed
// ---------------------------------------------------------------------------
__global__ __launch_bounds__(256) void k_zproj(
    const float* __restrict__ Hj, const float* __restrict__ Hi,
    const float* __restrict__ pjw, const float* __restrict__ piw,
    const float* __restrict__ sw1, const float* __restrict__ sb1,
    float* __restrict__ Zj, float* __restrict__ ZiT,
    float* __restrict__ A, float* __restrict__ BtT)
{
    int bs = blockIdx.x; int b = bs >> 9; int s = bs & 511;
    __shared__ float hj[HH], hi[HH], zj[DD], zi[DD];
    int tid = threadIdx.x;
    for (int i = tid; i < HH; i += 256) {
        hj[i] = Hj[(size_t)bs*HH + i];
        hi[i] = Hi[(size_t)bs*HH + i];
    }
    __syncthreads();
    int wid = tid >> 6, lane = tid & 63;
    for (int o = wid; o < 2*DD; o += 4) {
        int isJ = (o < DD); int d = isJ ? o : o - DD;
        const float* w = (isJ ? pjw : piw) + (size_t)d * HH;
        const float* x = isJ ? hj : hi;
        float acc = 0.f;
        #pragma unroll
        for (int k = 0; k < HH/64; ++k) { int h = lane + 64*k; acc = fmaf(x[h], w[h], acc); }
        #pragma unroll
        for (int off = 32; off > 0; off >>= 1) acc += __shfl_down(acc, off);
        if (lane == 0) { if (isJ) zj[d] = acc; else zi[d] = acc; }
    }
    __syncthreads();
    if (tid < DD) Zj[(size_t)bs*DD + tid] = zj[tid];
    else if (tid < 2*DD) { int d = tid - DD; ZiT[((size_t)b*DD + d)*SS + s] = zi[d]; }
    if (tid < MM) {
        float acc = sb1[tid];
        #pragma unroll
        for (int d = 0; d < DD; ++d) acc = fmaf(zj[d], sw1[tid*96 + d], acc);
        A[(size_t)bs*MM + tid] = acc;
    } else if (tid < 2*MM) {
        int m = tid - MM;
        float acc = 0.f;
        #pragma unroll
        for (int d = 0; d < DD; ++d) acc = fmaf(zi[d], sw1[m*96 + DD + d], acc);
        BtT[((size_t)b*MM + m)*SS + s] = acc;
    }
}

// ---------------------------------------------------------------------------
// K2: pairwise scorer + softmax -> probs.  One block per (b,s); thread owns
// t and t+256 (shared weight LDS reads amortized over 2 FMAs).
// ---------------------------------------------------------------------------
__global__ __launch_bounds__(256) void k_pair(
    const float* __restrict__ Zj, const float* __restrict__ ZiT,
    const float* __restrict__ A, const float* __restrict__ BtT,
    const float* __restrict__ sw1, const float* __restrict__ sw2,
    const float* __restrict__ sb2, const float* __restrict__ mask,
    float* __restrict__ probs)
{
    int bs = blockIdx.x; int b = bs >> 9;
    int tid = threadIdx.x;
    __shared__ float wcd[MM*48];
    __shared__ float zjs[DD], aa[MM], w2s[MM];
    __shared__ float red[256];
    for (int i = tid; i < MM*48; i += 256) {
        int m = i / 48, d = i % 48;
        wcd[i] = sw1[m*96 + 48 + d];   // [Wc | Wd] columns 48..95
    }
    if (tid < DD) zjs[tid] = Zj[(size_t)bs*DD + tid];
    if (tid < MM) { aa[tid] = A[(size_t)bs*MM + tid]; w2s[tid] = sw2[tid]; }
    __syncthreads();

    int t0 = tid, t1 = tid + 256;
    float ef0[48], ef1[48];
    #pragma unroll
    for (int d = 0; d < DD; ++d) {
        float zj = zjs[d];
        const float* zp = ZiT + ((size_t)b*DD + d)*SS;
        float zi0 = zp[t0], zi1 = zp[t1];
        ef0[d] = zj * zi0; ef0[DD + d] = fabsf(zj - zi0);
        ef1[d] = zj * zi1; ef1[DD + d] = fabsf(zj - zi1);
    }
    float sb2v = sb2[0];
    float logit0 = sb2v, logit1 = sb2v;
    const float* btp = BtT + (size_t)b*MM*SS;
    for (int m = 0; m < MM; ++m) {
        float am = aa[m];
        float b0 = btp[m*SS + t0], b1 = btp[m*SS + t1];
        float acc0 = am + b0, acc1 = am + b1;
        const float* w = &wcd[m*48];
        #pragma unroll
        for (int d = 0; d < 48; ++d) {
            float wd = w[d];
            acc0 = fmaf(wd, ef0[d], acc0);
            acc1 = fmaf(wd, ef1[d], acc1);
        }
        float sw = w2s[m];
        logit0 = fmaf(fmaxf(acc0, 0.f), sw, logit0);
        logit1 = fmaf(fmaxf(acc1, 0.f), sw, logit1);
    }
    const float NEGF = -3.4028234663852886e38f;
    logit0 += (1.f - mask[b*SS + t0]) * NEGF;
    logit1 += (1.f - mask[b*SS + t1]) * NEGF;

    // softmax over 512 (each thread holds 2 logits)
    red[tid] = fmaxf(logit0, logit1);
    __syncthreads();
    for (int off = 128; off > 0; off >>= 1) {
        if (tid < off) red[tid] = fmaxf(red[tid], red[tid+off]);
        __syncthreads();
    }
    float mx = red[0];
    __syncthreads();
    float e0 = __expf(logit0 - mx), e1 = __expf(logit1 - mx);
    red[tid] = e0 + e1;
    __syncthreads();
    for (int off = 128; off > 0; off >>= 1) {
        if (tid < off) red[tid] += red[tid+off];
        __syncthreads();
    }
    float inv = 1.f / red[0];
    probs[(size_t)bs*SS + t0] = e0 * inv;
    probs[(size_t)bs*SS + t1] = e1 * inv;
}

// ---------------------------------------------------------------------------
// K3: ctx[b,s,h] = sum_t probs[b,s,t] * H_i[b,t,h].  Tiles 32s x 128h, TK=32.
// ---------------------------------------------------------------------------
__global__ __launch_bounds__(256) void k_ctx(
    const float* __restrict__ probs, const float* __restrict__ Hi,
    float* __restrict__ ctx)
{
    int b = blockIdx.z;
    int s0 = blockIdx.y * 32;
    int h0 = blockIdx.x * 128;
    int tid = threadIdx.x;
    int tx = tid & 31, ty = tid >> 5;
    __shared__ float pt[32][33];
    __shared__ float ht[32][128];
    float4 acc[4];
    #pragma unroll
    for (int i = 0; i < 4; ++i) acc[i] = make_float4(0.f, 0.f, 0.f, 0.f);
    for (int t0 = 0; t0 < SS; t0 += 32) {
        #pragma unroll
        for (int i = 0; i < 4; ++i) {
            int idx = tid + i*256; int sl = idx >> 5, tl = idx & 31;
            pt[sl][tl] = probs[((size_t)b*SS + s0 + sl)*SS + t0 + tl];
        }
        #pragma unroll
        for (int i = 0; i < 16; ++i) {
            int idx = tid + i*256; int tl = idx >> 7, hl = idx & 127;
            ht[tl][hl] = Hi[((size_t)b*SS + t0 + tl)*HH + h0 + hl];
        }
        __syncthreads();
        #pragma unroll
        for (int kk = 0; kk < 32; ++kk) {
            float4 hv = *(const float4*)&ht[kk][tx*4];
            #pragma unroll
            for (int i = 0; i < 4; ++i) {
                float p = pt[ty*4 + i][kk];
                acc[i].x = fmaf(p, hv.x, acc[i].x);
                acc[i].y = fmaf(p, hv.y, acc[i].y);
                acc[i].z = fmaf(p, hv.z, acc[i].z);
                acc[i].w = fmaf(p, hv.w, acc[i].w);
            }
        }
        __syncthreads();
    }
    #pragma unroll
    for (int i = 0; i < 4; ++i) {
        int s = s0 + ty*4 + i;
        *(float4*)&ctx[((size_t)b*SS + s)*HH + h0 + tx*4] = acc[i];
    }
}

// ---------------------------------------------------------------------------
// Transpose RxC -> CxR (dims multiples of 32)
// ---------------------------------------------------------------------------
__global__ __launch_bounds__(256) void k_transpose(
    const float* __restrict__ in, float* __restrict__ out, int R, int C)
{
    __shared__ float tile[32][33];
    int r0 = blockIdx.y * 32, c0 = blockIdx.x * 32;
    int tx = threadIdx.x & 31, ty = threadIdx.x >> 5;
    for (int i = ty; i < 32; i += 8) tile[i][tx] = in[(size_t)(r0 + i)*C + c0 + tx];
    __syncthreads();
    for (int i = ty; i < 32; i += 8) out[(size_t)(c0 + i)*R + r0 + tx] = tile[tx][i];
}

// ---------------------------------------------------------------------------
// G1: h1 = relu([ctx | Hj | ctx*Hj] @ w1T + vb1).  64n x 64o tiles, TK=16.
// ---------------------------------------------------------------------------
__global__ __launch_bounds__(256) void k_gemm1(
    const float* __restrict__ ctx, const float* __restrict__ Hj,
    const float* __restrict__ w1T, const float* __restrict__ vb1,
    float* __restrict__ h1)
{
    int o0 = blockIdx.x * 64;
    int n0 = blockIdx.y * 64;
    int tid = threadIdx.x;
    int tx = tid & 15, ty = tid >> 4;
    __shared__ float xt[16][65];
    __shared__ float wt[16][68];
    float4 acc[4];
    #pragma unroll
    for (int i = 0; i < 4; ++i) acc[i] = make_float4(0.f, 0.f, 0.f, 0.f);
    for (int k0 = 0; k0 < K3H; k0 += 16) {
        int region = k0 / HH;         // 0: ctx, 1: Hj, 2: ctx*Hj (768%16==0)
        int kb = k0 - region*HH;
        {
            int nn = tid >> 2, kk = (tid & 3) * 4;
            int n = n0 + nn;
            float4 v;
            if (region == 0)      v = *(const float4*)&ctx[(size_t)n*HH + kb + kk];
            else if (region == 1) v = *(const float4*)&Hj[(size_t)n*HH + kb + kk];
            else {
                float4 c = *(const float4*)&ctx[(size_t)n*HH + kb + kk];
                float4 h = *(const float4*)&Hj[(size_t)n*HH + kb + kk];
                v = make_float4(c.x*h.x, c.y*h.y, c.z*h.z, c.w*h.w);
            }
            xt[kk+0][nn] = v.x; xt[kk+1][nn] = v.y; xt[kk+2][nn] = v.z; xt[kk+3][nn] = v.w;
        }
        {
            int kk = tid >> 4, oo = (tid & 15) * 4;
            *(float4*)&wt[kk][oo] = *(const float4*)&w1T[(size_t)(k0 + kk)*OH + o0 + oo];
        }
        __syncthreads();
        #pragma unroll
        for (int kk = 0; kk < 16; ++kk) {
            float4 wv = *(const float4*)&wt[kk][tx*4];
            float xv[4];
            #pragma unroll
            for (int i = 0; i < 4; ++i) xv[i] = xt[kk][ty*4 + i];
            #pragma unroll
            for (int i = 0; i < 4; ++i) {
                acc[i].x = fmaf(xv[i], wv.x, acc[i].x);
                acc[i].y = fmaf(xv[i], wv.y, acc[i].y);
                acc[i].z = fmaf(xv[i], wv.z, acc[i].z);
                acc[i].w = fmaf(xv[i], wv.w, acc[i].w);
            }
        }
        __syncthreads();
    }
    float4 bias = *(const float4*)&vb1[o0 + tx*4];
    #pragma unroll
    for (int i = 0; i < 4; ++i) {
        float4 r;
        r.x = fmaxf(acc[i].x + bias.x, 0.f);
        r.y = fmaxf(acc[i].y + bias.y, 0.f);
        r.z = fmaxf(acc[i].z + bias.z, 0.f);
        r.w = fmaxf(acc[i].w + bias.w, 0.f);
        *(float4*)&h1[(size_t)(n0 + ty*4 + i)*OH + o0 + tx*4] = r;
    }
}

// ---------------------------------------------------------------------------
// G2: out = alpha * (h1 @ w2T + vb2)
// ---------------------------------------------------------------------------
__global__ __launch_bounds__(256) void k_gemm2(
    const float* __restrict__ h1, const float* __restrict__ w2T,
    const float* __restrict__ vb2, const float* __restrict__ alpha,
    float* __restrict__ out)
{
    int o0 = blockIdx.x * 64;
    int n0 = blockIdx.y * 64;
    int tid = threadIdx.x;
    int tx = tid & 15, ty = tid >> 4;
    __shared__ float xt[16][65];
    __shared__ float wt[16][68];
    float4 acc[4];
    #pragma unroll
    for (int i = 0; i < 4; ++i) acc[i] = make_float4(0.f, 0.f, 0.f, 0.f);
    for (int k0 = 0; k0 < OH; k0 += 16) {
        {
            int nn = tid >> 2, kk = (tid & 3) * 4;
            float4 v = *(const float4*)&h1[(size_t)(n0 + nn)*OH + k0 + kk];
            xt[kk+0][nn] = v.x; xt[kk+1][nn] = v.y; xt[kk+2][nn] = v.z; xt[kk+3][nn] = v.w;
        }
        {
            int kk = tid >> 4, oo = (tid & 15) * 4;
            *(float4*)&wt[kk][oo] = *(const float4*)&w2T[(size_t)(k0 + kk)*HH + o0 + oo];
        }
        __syncthreads();
        #pragma unroll
        for (int kk = 0; kk < 16; ++kk) {
            float4 wv = *(const float4*)&wt[kk][tx*4];
            float xv[4];
            #pragma unroll
            for (int i = 0; i < 4; ++i) xv[i] = xt[kk][ty*4 + i];
            #pragma unroll
            for (int i = 0; i < 4; ++i) {
                acc[i].x = fmaf(xv[i], wv.x, acc[i].x);
                acc[i].y = fmaf(xv[i], wv.y, acc[i].y);
                acc[i].z = fmaf(xv[i], wv.z, acc[i].z);
                acc[i].w = fmaf(xv[i], wv.w, acc[i].w);
            }
        }
        __syncthreads();
    }
    float al = alpha[0];
    float4 bias = *(const float4*)&vb2[o0 + tx*4];
    #pragma unroll
    for (int i = 0; i < 4; ++i) {
        float4 r;
        r.x = al * (acc[i].x + bias.x);
        r.y = al * (acc[i].y + bias.y);
        r.z = al * (acc[i].z + bias.z);
        r.w = al * (acc[i].w + bias.w);
        *(float4*)&out[(size_t)(n0 + ty*4 + i)*HH + o0 + tx*4] = r;
    }
}

// ---------------------------------------------------------------------------
extern "C" void kernel_launch(void* const* d_in, const int* in_sizes, int n_in,
                              void* d_out, int out_size, void* d_ws, size_t ws_size,
                              hipStream_t stream) {
    const float* Hj    = (const float*)d_in[0];
    const float* Hi    = (const float*)d_in[1];
    const float* amask = (const float*)d_in[2];
    const float* pjw   = (const float*)d_in[3];
    const float* piw   = (const float*)d_in[4];
    const float* sw1   = (const float*)d_in[5];
    const float* sb1   = (const float*)d_in[6];
    const float* sw2   = (const float*)d_in[7];
    const float* sb2   = (const float*)d_in[8];
    const float* vw1   = (const float*)d_in[9];
    const float* vb1   = (const float*)d_in[10];
    const float* vw2   = (const float*)d_in[11];
    const float* vb2   = (const float*)d_in[12];
    const float* alpha = (const float*)d_in[13];
    float* out = (float*)d_out;

    float* ws    = (float*)d_ws;
    float* Zj    = ws + OFF_ZJ;
    float* ZiT   = ws + OFF_ZIT;
    float* A     = ws + OFF_A;
    float* BtT   = ws + OFF_BTT;
    float* probs = ws + OFF_PROBS;
    float* ctx   = ws + OFF_CTX;
    float* h1    = ws + OFF_H1;
    float* w1T   = ws + OFF_W1T;
    float* w2T   = ws + OFF_W2T;

    k_zproj<<<BB*SS, 256, 0, stream>>>(Hj, Hi, pjw, piw, sw1, sb1, Zj, ZiT, A, BtT);
    k_transpose<<<dim3(K3H/32, OH/32), 256, 0, stream>>>(vw1, w1T, OH, K3H);
    k_transpose<<<dim3(OH/32, HH/32), 256, 0, stream>>>(vw2, w2T, HH, OH);
    k_pair<<<BB*SS, 256, 0, stream>>>(Zj, ZiT, A, BtT, sw1, sw2, sb2, amask, probs);
    k_ctx<<<dim3(HH/128, SS/32, BB), 256, 0, stream>>>(probs, Hi, ctx);
    k_gemm1<<<dim3(OH/64, BB*SS/64), 256, 0, stream>>>(ctx, Hj, w1T, vb1, h1);
    k_gemm2<<<dim3(HH/64, BB*SS/64), 256, 0, stream>>>(h1, w2T, vb2, alpha, out);
}

// Round 2
// 357.091 us; speedup vs baseline: 1.4514x; 1.4514x over previous
//
#include <hip/hip_runtime.h>
#include <hip/hip_bf16.h>
#include <math.h>

#define BB 4
#define SS 512
#define HH 768
#define DD 24
#define MM 96
#define OH 768      // OUT_HID
#define K3H 2304    // 3*H

typedef unsigned short u16;
typedef short bf16x8 __attribute__((ext_vector_type(8)));
typedef float f32x4 __attribute__((ext_vector_type(4)));
typedef u16 u16x4 __attribute__((ext_vector_type(4)));

// workspace layout: fp32 region (offsets in floats)
#define OFF_ZJ    0
#define OFF_ZIT   (OFF_ZJ    + BB*SS*DD)      // [b][d][t]
#define OFF_A     (OFF_ZIT   + BB*SS*DD)      // [b][s][m]  (includes s_b1)
#define OFF_BTT   (OFF_A     + BB*SS*MM)      // [b][m][t]
#define OFF_PROBS (OFF_BTT   + BB*SS*MM)      // [b][s][t]
#define OFF_CTX   (OFF_PROBS + BB*SS*SS)      // [b][s][h]
#define F32_END   (OFF_CTX   + BB*SS*HH)      // = 3,112,960 floats (12,451,840 B, 16B-aligned)
// bf16 region (offsets in u16, from bf16 base)
#define MB_MSGIN  0                            // [2048][2304]
#define MB_H1     (MB_MSGIN + BB*SS*K3H)       // [2048][768]
#define MB_W1     (MB_H1    + BB*SS*OH)        // [768][2304]
#define MB_W2     (MB_W1    + OH*K3H)          // [768][768]

__device__ inline u16 f2bf(float x) {
    union { float f; unsigned u; } v; v.f = x;
    unsigned r = v.u + 0x7fffu + ((v.u >> 16) & 1u);   // RNE
    return (u16)(r >> 16);
}

// ---------------------------------------------------------------------------
// K1: Z projections + per-row A (Zj·Wa^T + s_b1) and Bt (Zi·Wb^T), transposed
// ---------------------------------------------------------------------------
__global__ __launch_bounds__(256) void k_zproj(
    const float* __restrict__ Hj, const float* __restrict__ Hi,
    const float* __restrict__ pjw, const float* __restrict__ piw,
    const float* __restrict__ sw1, const float* __restrict__ sb1,
    float* __restrict__ Zj, float* __restrict__ ZiT,
    float* __restrict__ A, float* __restrict__ BtT)
{
    int bs = blockIdx.x; int b = bs >> 9; int s = bs & 511;
    __shared__ float hj[HH], hi[HH], zj[DD], zi[DD];
    int tid = threadIdx.x;
    for (int i = tid; i < HH; i += 256) {
        hj[i] = Hj[(size_t)bs*HH + i];
        hi[i] = Hi[(size_t)bs*HH + i];
    }
    __syncthreads();
    int wid = tid >> 6, lane = tid & 63;
    for (int o = wid; o < 2*DD; o += 4) {
        int isJ = (o < DD); int d = isJ ? o : o - DD;
        const float* w = (isJ ? pjw : piw) + (size_t)d * HH;
        const float* x = isJ ? hj : hi;
        float acc = 0.f;
        #pragma unroll
        for (int k = 0; k < HH/64; ++k) { int h = lane + 64*k; acc = fmaf(x[h], w[h], acc); }
        #pragma unroll
        for (int off = 32; off > 0; off >>= 1) acc += __shfl_down(acc, off);
        if (lane == 0) { if (isJ) zj[d] = acc; else zi[d] = acc; }
    }
    __syncthreads();
    if (tid < DD) Zj[(size_t)bs*DD + tid] = zj[tid];
    else if (tid < 2*DD) { int d = tid - DD; ZiT[((size_t)b*DD + d)*SS + s] = zi[d]; }
    if (tid < MM) {
        float acc = sb1[tid];
        #pragma unroll
        for (int d = 0; d < DD; ++d) acc = fmaf(zj[d], sw1[tid*96 + d], acc);
        A[(size_t)bs*MM + tid] = acc;
    } else if (tid < 2*MM) {
        int m = tid - MM;
        float acc = 0.f;
        #pragma unroll
        for (int d = 0; d < DD; ++d) acc = fmaf(zi[d], sw1[m*96 + DD + d], acc);
        BtT[((size_t)b*MM + m)*SS + s] = acc;
    }
}

// ---------------------------------------------------------------------------
// K2: pairwise scorer + softmax -> probs (fp32, unchanged this round)
// ---------------------------------------------------------------------------
__global__ __launch_bounds__(256) void k_pair(
    const float* __restrict__ Zj, const float* __restrict__ ZiT,
    const float* __restrict__ A, const float* __restrict__ BtT,
    const float* __restrict__ sw1, const float* __restrict__ sw2,
    const float* __restrict__ sb2, const float* __restrict__ mask,
    float* __restrict__ probs)
{
    int bs = blockIdx.x; int b = bs >> 9;
    int tid = threadIdx.x;
    __shared__ float wcd[MM*48];
    __shared__ float zjs[DD], aa[MM], w2s[MM];
    __shared__ float red[256];
    for (int i = tid; i < MM*48; i += 256) {
        int m = i / 48, d = i % 48;
        wcd[i] = sw1[m*96 + 48 + d];   // [Wc | Wd] columns 48..95
    }
    if (tid < DD) zjs[tid] = Zj[(size_t)bs*DD + tid];
    if (tid < MM) { aa[tid] = A[(size_t)bs*MM + tid]; w2s[tid] = sw2[tid]; }
    __syncthreads();

    int t0 = tid, t1 = tid + 256;
    float ef0[48], ef1[48];
    #pragma unroll
    for (int d = 0; d < DD; ++d) {
        float zj = zjs[d];
        const float* zp = ZiT + ((size_t)b*DD + d)*SS;
        float zi0 = zp[t0], zi1 = zp[t1];
        ef0[d] = zj * zi0; ef0[DD + d] = fabsf(zj - zi0);
        ef1[d] = zj * zi1; ef1[DD + d] = fabsf(zj - zi1);
    }
    float sb2v = sb2[0];
    float logit0 = sb2v, logit1 = sb2v;
    const float* btp = BtT + (size_t)b*MM*SS;
    for (int m = 0; m < MM; ++m) {
        float am = aa[m];
        float b0 = btp[m*SS + t0], b1 = btp[m*SS + t1];
        float acc0 = am + b0, acc1 = am + b1;
        const float* w = &wcd[m*48];
        #pragma unroll
        for (int d = 0; d < 48; ++d) {
            float wd = w[d];
            acc0 = fmaf(wd, ef0[d], acc0);
            acc1 = fmaf(wd, ef1[d], acc1);
        }
        float sw = w2s[m];
        logit0 = fmaf(fmaxf(acc0, 0.f), sw, logit0);
        logit1 = fmaf(fmaxf(acc1, 0.f), sw, logit1);
    }
    const float NEGF = -3.4028234663852886e38f;
    logit0 += (1.f - mask[b*SS + t0]) * NEGF;
    logit1 += (1.f - mask[b*SS + t1]) * NEGF;

    red[tid] = fmaxf(logit0, logit1);
    __syncthreads();
    for (int off = 128; off > 0; off >>= 1) {
        if (tid < off) red[tid] = fmaxf(red[tid], red[tid+off]);
        __syncthreads();
    }
    float mx = red[0];
    __syncthreads();
    float e0 = __expf(logit0 - mx), e1 = __expf(logit1 - mx);
    red[tid] = e0 + e1;
    __syncthreads();
    for (int off = 128; off > 0; off >>= 1) {
        if (tid < off) red[tid] += red[tid+off];
        __syncthreads();
    }
    float inv = 1.f / red[0];
    probs[(size_t)bs*SS + t0] = e0 * inv;
    probs[(size_t)bs*SS + t1] = e1 * inv;
}

// ---------------------------------------------------------------------------
// K3: ctx[b,s,h] = sum_t probs[b,s,t] * H_i[b,t,h].  (fp32, unchanged)
// ---------------------------------------------------------------------------
__global__ __launch_bounds__(256) void k_ctx(
    const float* __restrict__ probs, const float* __restrict__ Hi,
    float* __restrict__ ctx)
{
    int b = blockIdx.z;
    int s0 = blockIdx.y * 32;
    int h0 = blockIdx.x * 128;
    int tid = threadIdx.x;
    int tx = tid & 31, ty = tid >> 5;
    __shared__ float pt[32][33];
    __shared__ float ht[32][128];
    float4 acc[4];
    #pragma unroll
    for (int i = 0; i < 4; ++i) acc[i] = make_float4(0.f, 0.f, 0.f, 0.f);
    for (int t0 = 0; t0 < SS; t0 += 32) {
        #pragma unroll
        for (int i = 0; i < 4; ++i) {
            int idx = tid + i*256; int sl = idx >> 5, tl = idx & 31;
            pt[sl][tl] = probs[((size_t)b*SS + s0 + sl)*SS + t0 + tl];
        }
        #pragma unroll
        for (int i = 0; i < 16; ++i) {
            int idx = tid + i*256; int tl = idx >> 7, hl = idx & 127;
            ht[tl][hl] = Hi[((size_t)b*SS + t0 + tl)*HH + h0 + hl];
        }
        __syncthreads();
        #pragma unroll
        for (int kk = 0; kk < 32; ++kk) {
            float4 hv = *(const float4*)&ht[kk][tx*4];
            #pragma unroll
            for (int i = 0; i < 4; ++i) {
                float p = pt[ty*4 + i][kk];
                acc[i].x = fmaf(p, hv.x, acc[i].x);
                acc[i].y = fmaf(p, hv.y, acc[i].y);
                acc[i].z = fmaf(p, hv.z, acc[i].z);
                acc[i].w = fmaf(p, hv.w, acc[i].w);
            }
        }
        __syncthreads();
    }
    #pragma unroll
    for (int i = 0; i < 4; ++i) {
        int s = s0 + ty*4 + i;
        *(float4*)&ctx[((size_t)b*SS + s)*HH + h0 + tx*4] = acc[i];
    }
}

// ---------------------------------------------------------------------------
// cast fp32 -> bf16, 8 elements/thread
// ---------------------------------------------------------------------------
__global__ __launch_bounds__(256) void k_cast_bf(
    const float* __restrict__ in, u16* __restrict__ out, int n)
{
    int i = (blockIdx.x*256 + threadIdx.x) * 8;
    if (i >= n) return;
    float4 a = *(const float4*)&in[i];
    float4 b = *(const float4*)&in[i+4];
    u16x4 lo = { f2bf(a.x), f2bf(a.y), f2bf(a.z), f2bf(a.w) };
    u16x4 hi = { f2bf(b.x), f2bf(b.y), f2bf(b.z), f2bf(b.w) };
    *(u16x4*)&out[i]   = lo;
    *(u16x4*)&out[i+4] = hi;
}

// ---------------------------------------------------------------------------
// build msg_in bf16 [2048][2304] = [bf(ctx) | bf(Hj) | bf(ctx*Hj)]
// ---------------------------------------------------------------------------
__global__ __launch_bounds__(256) void k_msgin(
    const float* __restrict__ ctx, const float* __restrict__ Hj,
    u16* __restrict__ mbf)
{
    int idx = blockIdx.x*256 + threadIdx.x;   // one per 4 elements
    int n = idx / (HH/4); int kk = (idx % (HH/4)) * 4;
    float4 c = *(const float4*)&ctx[(size_t)n*HH + kk];
    float4 h = *(const float4*)&Hj[(size_t)n*HH + kk];
    u16x4 vc = { f2bf(c.x), f2bf(c.y), f2bf(c.z), f2bf(c.w) };
    u16x4 vh = { f2bf(h.x), f2bf(h.y), f2bf(h.z), f2bf(h.w) };
    u16x4 vp = { f2bf(c.x*h.x), f2bf(c.y*h.y), f2bf(c.z*h.z), f2bf(c.w*h.w) };
    u16* base = mbf + (size_t)n*K3H + kk;
    *(u16x4*)(base)        = vc;
    *(u16x4*)(base + HH)   = vh;
    *(u16x4*)(base + 2*HH) = vp;
}

// ---------------------------------------------------------------------------
// MFMA gemm_bt: C[n][o] = epi( sum_k A[n][k]*B[o][k] ).  64x64 tile, BK=32.
// A: [N][K] bf16, B: [O][K] bf16 (row-major, K contiguous).
// LDS row stride 40 u16 (80 B): 2-way bank alias only (free per m136).
// ---------------------------------------------------------------------------
#define LDA 40
__global__ __launch_bounds__(256) void k_mfma_gemm1(
    const u16* __restrict__ Abf, const u16* __restrict__ Bbf,
    const float* __restrict__ bias, u16* __restrict__ Cbf)
{
    int o0 = blockIdx.x * 64;
    int n0 = blockIdx.y * 64;
    int tid = threadIdx.x;
    __shared__ __align__(16) u16 As[64*LDA];
    __shared__ __align__(16) u16 Bs[64*LDA];
    int row = tid >> 2, chunk = tid & 3;
    int wave = tid >> 6, lane = tid & 63;
    int wr = (wave >> 1) * 32, wc = (wave & 1) * 32;
    int q = lane >> 4, l16 = lane & 15;
    f32x4 acc00 = {}, acc01 = {}, acc10 = {}, acc11 = {};
    const u16* ag = Abf + (size_t)(n0 + row)*K3H + chunk*8;
    const u16* bg = Bbf + (size_t)(o0 + row)*K3H + chunk*8;
    int lidx = row*LDA + chunk*8;
    for (int k0 = 0; k0 < K3H; k0 += 32) {
        *(uint4*)&As[lidx] = *(const uint4*)(ag + k0);
        *(uint4*)&Bs[lidx] = *(const uint4*)(bg + k0);
        __syncthreads();
        bf16x8 a0 = *(const bf16x8*)&As[(wr      + l16)*LDA + q*8];
        bf16x8 a1 = *(const bf16x8*)&As[(wr + 16 + l16)*LDA + q*8];
        bf16x8 b0 = *(const bf16x8*)&Bs[(wc      + l16)*LDA + q*8];
        bf16x8 b1 = *(const bf16x8*)&Bs[(wc + 16 + l16)*LDA + q*8];
        acc00 = __builtin_amdgcn_mfma_f32_16x16x32_bf16(a0, b0, acc00, 0,0,0);
        acc01 = __builtin_amdgcn_mfma_f32_16x16x32_bf16(a0, b1, acc01, 0,0,0);
        acc10 = __builtin_amdgcn_mfma_f32_16x16x32_bf16(a1, b0, acc10, 0,0,0);
        acc11 = __builtin_amdgcn_mfma_f32_16x16x32_bf16(a1, b1, acc11, 0,0,0);
        __syncthreads();
    }
    // epilogue: +bias, relu, store bf16.  D layout: col=l16 (o), row=q*4+r (m)
    #pragma unroll
    for (int rt = 0; rt < 2; ++rt) {
        #pragma unroll
        for (int ct = 0; ct < 2; ++ct) {
            const f32x4* ac = rt ? (ct ? &acc11 : &acc10) : (ct ? &acc01 : &acc00);
            int o = o0 + wc + ct*16 + l16;
            float bv = bias[o];
            #pragma unroll
            for (int r = 0; r < 4; ++r) {
                int m = n0 + wr + rt*16 + q*4 + r;
                float v = fmaxf((*ac)[r] + bv, 0.f);
                Cbf[(size_t)m*OH + o] = f2bf(v);
            }
        }
    }
}

__global__ __launch_bounds__(256) void k_mfma_gemm2(
    const u16* __restrict__ Abf, const u16* __restrict__ Bbf,
    const float* __restrict__ bias, const float* __restrict__ alpha,
    float* __restrict__ out)
{
    int o0 = blockIdx.x * 64;
    int n0 = blockIdx.y * 64;
    int tid = threadIdx.x;
    __shared__ __align__(16) u16 As[64*LDA];
    __shared__ __align__(16) u16 Bs[64*LDA];
    int row = tid >> 2, chunk = tid & 3;
    int wave = tid >> 6, lane = tid & 63;
    int wr = (wave >> 1) * 32, wc = (wave & 1) * 32;
    int q = lane >> 4, l16 = lane & 15;
    f32x4 acc00 = {}, acc01 = {}, acc10 = {}, acc11 = {};
    const u16* ag = Abf + (size_t)(n0 + row)*OH + chunk*8;
    const u16* bg = Bbf + (size_t)(o0 + row)*OH + chunk*8;
    int lidx = row*LDA + chunk*8;
    for (int k0 = 0; k0 < OH; k0 += 32) {
        *(uint4*)&As[lidx] = *(const uint4*)(ag + k0);
        *(uint4*)&Bs[lidx] = *(const uint4*)(bg + k0);
        __syncthreads();
        bf16x8 a0 = *(const bf16x8*)&As[(wr      + l16)*LDA + q*8];
        bf16x8 a1 = *(const bf16x8*)&As[(wr + 16 + l16)*LDA + q*8];
        bf16x8 b0 = *(const bf16x8*)&Bs[(wc      + l16)*LDA + q*8];
        bf16x8 b1 = *(const bf16x8*)&Bs[(wc + 16 + l16)*LDA + q*8];
        acc00 = __builtin_amdgcn_mfma_f32_16x16x32_bf16(a0, b0, acc00, 0,0,0);
        acc01 = __builtin_amdgcn_mfma_f32_16x16x32_bf16(a0, b1, acc01, 0,0,0);
        acc10 = __builtin_amdgcn_mfma_f32_16x16x32_bf16(a1, b0, acc10, 0,0,0);
        acc11 = __builtin_amdgcn_mfma_f32_16x16x32_bf16(a1, b1, acc11, 0,0,0);
        __syncthreads();
    }
    float al = alpha[0];
    #pragma unroll
    for (int rt = 0; rt < 2; ++rt) {
        #pragma unroll
        for (int ct = 0; ct < 2; ++ct) {
            const f32x4* ac = rt ? (ct ? &acc11 : &acc10) : (ct ? &acc01 : &acc00);
            int o = o0 + wc + ct*16 + l16;
            float bv = bias[o];
            #pragma unroll
            for (int r = 0; r < 4; ++r) {
                int m = n0 + wr + rt*16 + q*4 + r;
                out[(size_t)m*HH + o] = al * ((*ac)[r] + bv);
            }
        }
    }
}

// ---------------------------------------------------------------------------
extern "C" void kernel_launch(void* const* d_in, const int* in_sizes, int n_in,
                              void* d_out, int out_size, void* d_ws, size_t ws_size,
                              hipStream_t stream) {
    const float* Hj    = (const float*)d_in[0];
    const float* Hi    = (const float*)d_in[1];
    const float* amask = (const float*)d_in[2];
    const float* pjw   = (const float*)d_in[3];
    const float* piw   = (const float*)d_in[4];
    const float* sw1   = (const float*)d_in[5];
    const float* sb1   = (const float*)d_in[6];
    const float* sw2   = (const float*)d_in[7];
    const float* sb2   = (const float*)d_in[8];
    const float* vw1   = (const float*)d_in[9];
    const float* vb1   = (const float*)d_in[10];
    const float* vw2   = (const float*)d_in[11];
    const float* vb2   = (const float*)d_in[12];
    const float* alpha = (const float*)d_in[13];
    float* out = (float*)d_out;

    float* ws    = (float*)d_ws;
    float* Zj    = ws + OFF_ZJ;
    float* ZiT   = ws + OFF_ZIT;
    float* A     = ws + OFF_A;
    float* BtT   = ws + OFF_BTT;
    float* probs = ws + OFF_PROBS;
    float* ctx   = ws + OFF_CTX;
    u16* bfbase  = (u16*)(ws + F32_END);
    u16* msginb  = bfbase + MB_MSGIN;
    u16* h1b     = bfbase + MB_H1;
    u16* w1b     = bfbase + MB_W1;
    u16* w2b     = bfbase + MB_W2;

    k_zproj<<<BB*SS, 256, 0, stream>>>(Hj, Hi, pjw, piw, sw1, sb1, Zj, ZiT, A, BtT);
    k_cast_bf<<<(OH*K3H/8 + 255)/256, 256, 0, stream>>>(vw1, w1b, OH*K3H);
    k_cast_bf<<<(HH*OH/8 + 255)/256, 256, 0, stream>>>(vw2, w2b, HH*OH);
    k_pair<<<BB*SS, 256, 0, stream>>>(Zj, ZiT, A, BtT, sw1, sw2, sb2, amask, probs);
    k_ctx<<<dim3(HH/128, SS/32, BB), 256, 0, stream>>>(probs, Hi, ctx);
    k_msgin<<<(BB*SS*HH/4)/256, 256, 0, stream>>>(ctx, Hj, msginb);
    k_mfma_gemm1<<<dim3(OH/64, BB*SS/64), 256, 0, stream>>>(msginb, w1b, vb1, h1b);
    k_mfma_gemm2<<<dim3(HH/64, BB*SS/64), 256, 0, stream>>>(h1b, w2b, vb2, alpha, out);
}

// Round 3
// 267.538 us; speedup vs baseline: 1.9373x; 1.3347x over previous
//
#include <hip/hip_runtime.h>
#include <hip/hip_bf16.h>
#include <math.h>

#define BB 4
#define SS 512
#define HH 768
#define DD 24
#define MM 96
#define OH 768      // OUT_HID
#define K3H 2304    // 3*H

typedef unsigned short u16;
typedef short bf16x8 __attribute__((ext_vector_type(8)));
typedef float f32x4 __attribute__((ext_vector_type(4)));
typedef u16 u16x4 __attribute__((ext_vector_type(4)));

// fp32 workspace (offsets in floats)
#define OFF_ZJ    0                            // [bs][24]
#define OFF_ZIR   (OFF_ZJ  + BB*SS*DD)         // [bs][24]  (row-major Zi)
#define OFF_A     (OFF_ZIR + BB*SS*DD)         // [bs][96]  (Zj.Wa + b1)
#define F32_END   (OFF_A   + BB*SS*MM)         // 294912 floats
// bf16 workspace (offsets in u16 from bf16 base)
#define MB_MSGIN  0                            // [2048][2304]
#define MB_H1     (MB_MSGIN + BB*SS*K3H)       // [2048][768]
#define MB_W1     (MB_H1    + BB*SS*OH)        // [768][2304]
#define MB_W2     (MB_W1    + OH*K3H)          // [768][768]
#define MB_PROBS  (MB_W2    + OH*HH)           // [2048][512]
#define MB_HIT    (MB_PROBS + BB*SS*SS)        // [b][768][512]
#define MB_WS     (MB_HIT   + BB*HH*SS)        // [96][104] scorer B-matrix

#define LDX 104   // u16 stride for scorer LDS tiles (208 B: 16B-aligned, 2-way alias only)

__device__ inline u16 f2bf(float x) {
    union { float f; unsigned u; } v; v.f = x;
    unsigned r = v.u + 0x7fffu + ((v.u >> 16) & 1u);   // RNE
    return (u16)(r >> 16);
}

// ---------------------------------------------------------------------------
// K1: Z projections + A = Zj.Wa + b1 (fp32).  Zi kept row-major now.
// ---------------------------------------------------------------------------
__global__ __launch_bounds__(256) void k_zproj(
    const float* __restrict__ Hj, const float* __restrict__ Hi,
    const float* __restrict__ pjw, const float* __restrict__ piw,
    const float* __restrict__ sw1, const float* __restrict__ sb1,
    float* __restrict__ Zj, float* __restrict__ ZIR, float* __restrict__ A)
{
    int bs = blockIdx.x;
    __shared__ float hj[HH], hi[HH], zj[DD], zi[DD];
    int tid = threadIdx.x;
    for (int i = tid; i < HH; i += 256) {
        hj[i] = Hj[(size_t)bs*HH + i];
        hi[i] = Hi[(size_t)bs*HH + i];
    }
    __syncthreads();
    int wid = tid >> 6, lane = tid & 63;
    for (int o = wid; o < 2*DD; o += 4) {
        int isJ = (o < DD); int d = isJ ? o : o - DD;
        const float* w = (isJ ? pjw : piw) + (size_t)d * HH;
        const float* x = isJ ? hj : hi;
        float acc = 0.f;
        #pragma unroll
        for (int k = 0; k < HH/64; ++k) { int h = lane + 64*k; acc = fmaf(x[h], w[h], acc); }
        #pragma unroll
        for (int off = 32; off > 0; off >>= 1) acc += __shfl_down(acc, off);
        if (lane == 0) { if (isJ) zj[d] = acc; else zi[d] = acc; }
    }
    __syncthreads();
    if (tid < DD) Zj[(size_t)bs*DD + tid] = zj[tid];
    else if (tid < 2*DD) ZIR[(size_t)bs*DD + (tid - DD)] = zi[tid - DD];
    if (tid < MM) {
        float acc = sb1[tid];
        #pragma unroll
        for (int d = 0; d < DD; ++d) acc = fmaf(zj[d], sw1[tid*96 + d], acc);
        A[(size_t)bs*MM + tid] = acc;
    }
}

// ---------------------------------------------------------------------------
// prep: build static scorer B-matrix [96][LDX] bf16 = [Wc|Wd|Wb|0 A-slot|0pad]
// ---------------------------------------------------------------------------
__global__ __launch_bounds__(256) void k_prep(
    const float* __restrict__ sw1, u16* __restrict__ Wsb)
{
    for (int i = threadIdx.x; i < MM*LDX; i += 256) {
        int m = i / LDX, k = i % LDX;
        float v = 0.f;
        if (k < 24)      v = sw1[m*96 + 48 + k];        // Wc
        else if (k < 48) v = sw1[m*96 + 72 + (k-24)];   // Wd
        else if (k < 72) v = sw1[m*96 + 24 + (k-48)];   // Wb
        Wsb[i] = f2bf(v);
    }
}

// ---------------------------------------------------------------------------
// K2: MFMA pairwise scorer + softmax -> probs (bf16).
// One block per (b,s).  Features X[t][96] = [e|f|Zi|1|0], W[m][96] in LDS
// (A[s][m] patched into col 72).  logit[t] = relu(hid).w2 via lane-reduce.
// ---------------------------------------------------------------------------
__global__ __launch_bounds__(256) void k_pair_mfma(
    const float* __restrict__ Zj, const float* __restrict__ ZIR,
    const float* __restrict__ A, const u16* __restrict__ Wsb,
    const float* __restrict__ sw2, const float* __restrict__ sb2,
    const float* __restrict__ mask, u16* __restrict__ probsb)
{
    int bs = blockIdx.x; int b = bs >> 9;
    int tid = threadIdx.x;
    __shared__ __align__(16) u16 Ws[MM*LDX];
    __shared__ __align__(16) u16 Xs[128*LDX];
    __shared__ float zjs[DD];
    __shared__ float w2s[MM];
    __shared__ float logits[SS];
    __shared__ float red[256];

    for (int i = tid; i < MM*LDX; i += 256) Ws[i] = Wsb[i];
    if (tid < DD) zjs[tid] = Zj[(size_t)bs*DD + tid];
    if (tid < MM) w2s[tid] = sw2[tid];
    __syncthreads();
    if (tid < MM) Ws[tid*LDX + 72] = f2bf(A[(size_t)bs*MM + tid]);
    __syncthreads();

    int wave = tid >> 6, lane = tid & 63;
    int q = lane >> 4, l16 = lane & 15;
    // B fragments pinned in registers: 6 m-tiles x 3 k-steps
    bf16x8 bfr[6][3];
    #pragma unroll
    for (int mt = 0; mt < 6; ++mt)
        #pragma unroll
        for (int ks = 0; ks < 3; ++ks)
            bfr[mt][ks] = *(const bf16x8*)&Ws[(mt*16 + l16)*LDX + ks*32 + q*8];
    float w2v[6];
    #pragma unroll
    for (int mt = 0; mt < 6; ++mt) w2v[mt] = w2s[mt*16 + l16];
    float sb2v = sb2[0];

    for (int c = 0; c < 4; ++c) {
        // ---- build features for t in [c*128, (c+1)*128), wave-uniform halves
        {
            int tl = tid & 127, half = tid >> 7;
            const float* zr = ZIR + ((size_t)(b*SS) + c*128 + tl)*DD;
            float zi[24];
            #pragma unroll
            for (int i = 0; i < 6; ++i) *(float4*)&zi[i*4] = *(const float4*)&zr[i*4];
            u16* xrow = &Xs[tl*LDX];
            if (half == 0) {
                u16 tmp[48];
                #pragma unroll
                for (int d = 0; d < 24; ++d) {
                    float zj = zjs[d];
                    tmp[d]      = f2bf(zj * zi[d]);
                    tmp[24 + d] = f2bf(fabsf(zj - zi[d]));
                }
                #pragma unroll
                for (int i = 0; i < 12; ++i) *(u16x4*)&xrow[i*4] = *(const u16x4*)&tmp[i*4];
            } else {
                u16 tmp[56];
                #pragma unroll
                for (int d = 0; d < 24; ++d) tmp[d] = f2bf(zi[d]);
                tmp[24] = 0x3F80;   // 1.0 -> A column
                #pragma unroll
                for (int i = 25; i < 56; ++i) tmp[i] = 0;
                #pragma unroll
                for (int i = 0; i < 14; ++i) *(u16x4*)&xrow[48 + i*4] = *(const u16x4*)&tmp[i*4];
            }
        }
        __syncthreads();
        // ---- MFMA: each wave does 2 t-tiles of 16
        #pragma unroll
        for (int tt = 0; tt < 2; ++tt) {
            int tbase = wave*32 + tt*16;
            bf16x8 af[3];
            #pragma unroll
            for (int ks = 0; ks < 3; ++ks)
                af[ks] = *(const bf16x8*)&Xs[(tbase + l16)*LDX + ks*32 + q*8];
            f32x4 acc[6];
            #pragma unroll
            for (int mt = 0; mt < 6; ++mt) {
                f32x4 a = {};
                a = __builtin_amdgcn_mfma_f32_16x16x32_bf16(af[0], bfr[mt][0], a, 0,0,0);
                a = __builtin_amdgcn_mfma_f32_16x16x32_bf16(af[1], bfr[mt][1], a, 0,0,0);
                a = __builtin_amdgcn_mfma_f32_16x16x32_bf16(af[2], bfr[mt][2], a, 0,0,0);
                acc[mt] = a;
            }
            // epilogue: relu, dot w2, reduce across l16 -> logit[t]
            #pragma unroll
            for (int r = 0; r < 4; ++r) {
                float p = 0.f;
                #pragma unroll
                for (int mt = 0; mt < 6; ++mt)
                    p = fmaf(fmaxf(acc[mt][r], 0.f), w2v[mt], p);
                #pragma unroll
                for (int off = 1; off < 16; off <<= 1) p += __shfl_xor(p, off);
                if (l16 == 0) logits[c*128 + tbase + q*4 + r] = p;
            }
        }
        __syncthreads();
    }

    // ---- softmax over 512 logits
    int t0 = tid, t1 = tid + 256;
    const float NEGF = -3.4028234663852886e38f;
    float lg0 = logits[t0] + sb2v + (1.f - mask[b*SS + t0]) * NEGF;
    float lg1 = logits[t1] + sb2v + (1.f - mask[b*SS + t1]) * NEGF;
    red[tid] = fmaxf(lg0, lg1);
    __syncthreads();
    for (int off = 128; off > 0; off >>= 1) {
        if (tid < off) red[tid] = fmaxf(red[tid], red[tid+off]);
        __syncthreads();
    }
    float mx = red[0];
    __syncthreads();
    float e0 = __expf(lg0 - mx), e1 = __expf(lg1 - mx);
    red[tid] = e0 + e1;
    __syncthreads();
    for (int off = 128; off > 0; off >>= 1) {
        if (tid < off) red[tid] += red[tid+off];
        __syncthreads();
    }
    float inv = 1.f / red[0];
    probsb[(size_t)bs*SS + t0] = f2bf(e0 * inv);
    probsb[(size_t)bs*SS + t1] = f2bf(e1 * inv);
}

// ---------------------------------------------------------------------------
// transpose Hi -> HiT bf16 [b][h][t]
// ---------------------------------------------------------------------------
__global__ __launch_bounds__(256) void k_hit(
    const float* __restrict__ Hi, u16* __restrict__ HiTb)
{
    int b = blockIdx.z; int t0 = blockIdx.x * 32; int h0 = blockIdx.y * 32;
    __shared__ float tile[32][33];
    int tx = threadIdx.x & 31, ty = threadIdx.x >> 5;
    for (int i = ty; i < 32; i += 8)
        tile[i][tx] = Hi[((size_t)(b*SS) + t0 + i)*HH + h0 + tx];
    __syncthreads();
    for (int i = ty; i < 32; i += 8)
        HiTb[((size_t)b*HH + h0 + i)*SS + t0 + tx] = f2bf(tile[tx][i]);
}

// ---------------------------------------------------------------------------
// cast fp32 -> bf16, 8 elements/thread
// ---------------------------------------------------------------------------
__global__ __launch_bounds__(256) void k_cast_bf(
    const float* __restrict__ in, u16* __restrict__ out, int n)
{
    int i = (blockIdx.x*256 + threadIdx.x) * 8;
    if (i >= n) return;
    float4 a = *(const float4*)&in[i];
    float4 b = *(const float4*)&in[i+4];
    u16x4 lo = { f2bf(a.x), f2bf(a.y), f2bf(a.z), f2bf(a.w) };
    u16x4 hi = { f2bf(b.x), f2bf(b.y), f2bf(b.z), f2bf(b.w) };
    *(u16x4*)&out[i]   = lo;
    *(u16x4*)&out[i+4] = hi;
}

// ---------------------------------------------------------------------------
// K3: ctx via MFMA (probs bf16 @ HiT bf16), epilogue fused msg_in build:
// msginb[s][:] = [bf(ctx) | bf(Hj) | bf(ctx*Hj)]
// ---------------------------------------------------------------------------
#define LDA 40
__global__ __launch_bounds__(256) void k_ctx_mfma(
    const u16* __restrict__ probsb, const u16* __restrict__ HiTb,
    const float* __restrict__ Hj, u16* __restrict__ msginb)
{
    int b = blockIdx.z;
    int h0 = blockIdx.x * 64;
    int s0 = blockIdx.y * 64;
    int tid = threadIdx.x;
    __shared__ __align__(16) u16 As[64*LDA];
    __shared__ __align__(16) u16 Bs[64*LDA];
    int row = tid >> 2, chunk = tid & 3;
    int wave = tid >> 6, lane = tid & 63;
    int wr = (wave >> 1) * 32, wc = (wave & 1) * 32;
    int q = lane >> 4, l16 = lane & 15;
    f32x4 acc00 = {}, acc01 = {}, acc10 = {}, acc11 = {};
    const u16* ag = probsb + ((size_t)(b*SS) + s0 + row)*SS + chunk*8;
    const u16* bg = HiTb + ((size_t)b*HH + h0 + row)*SS + chunk*8;
    int lidx = row*LDA + chunk*8;
    for (int k0 = 0; k0 < SS; k0 += 32) {
        *(uint4*)&As[lidx] = *(const uint4*)(ag + k0);
        *(uint4*)&Bs[lidx] = *(const uint4*)(bg + k0);
        __syncthreads();
        bf16x8 a0 = *(const bf16x8*)&As[(wr      + l16)*LDA + q*8];
        bf16x8 a1 = *(const bf16x8*)&As[(wr + 16 + l16)*LDA + q*8];
        bf16x8 b0 = *(const bf16x8*)&Bs[(wc      + l16)*LDA + q*8];
        bf16x8 b1 = *(const bf16x8*)&Bs[(wc + 16 + l16)*LDA + q*8];
        acc00 = __builtin_amdgcn_mfma_f32_16x16x32_bf16(a0, b0, acc00, 0,0,0);
        acc01 = __builtin_amdgcn_mfma_f32_16x16x32_bf16(a0, b1, acc01, 0,0,0);
        acc10 = __builtin_amdgcn_mfma_f32_16x16x32_bf16(a1, b0, acc10, 0,0,0);
        acc11 = __builtin_amdgcn_mfma_f32_16x16x32_bf16(a1, b1, acc11, 0,0,0);
        __syncthreads();
    }
    #pragma unroll
    for (int rt = 0; rt < 2; ++rt) {
        #pragma unroll
        for (int ct = 0; ct < 2; ++ct) {
            const f32x4* ac = rt ? (ct ? &acc11 : &acc10) : (ct ? &acc01 : &acc00);
            int h = h0 + wc + ct*16 + l16;
            #pragma unroll
            for (int r = 0; r < 4; ++r) {
                int s = s0 + wr + rt*16 + q*4 + r;
                float v = (*ac)[r];
                float hj = Hj[((size_t)(b*SS) + s)*HH + h];
                u16* mb = msginb + (size_t)(b*SS + s)*K3H + h;
                mb[0]    = f2bf(v);
                mb[HH]   = f2bf(hj);
                mb[2*HH] = f2bf(v * hj);
            }
        }
    }
}

// ---------------------------------------------------------------------------
// MFMA gemm_bt: C = relu(A.B^T + bias) -> bf16   (64x64 tile, BK=32)
// ---------------------------------------------------------------------------
__global__ __launch_bounds__(256) void k_mfma_gemm1(
    const u16* __restrict__ Abf, const u16* __restrict__ Bbf,
    const float* __restrict__ bias, u16* __restrict__ Cbf)
{
    int o0 = blockIdx.x * 64;
    int n0 = blockIdx.y * 64;
    int tid = threadIdx.x;
    __shared__ __align__(16) u16 As[64*LDA];
    __shared__ __align__(16) u16 Bs[64*LDA];
    int row = tid >> 2, chunk = tid & 3;
    int wave = tid >> 6, lane = tid & 63;
    int wr = (wave >> 1) * 32, wc = (wave & 1) * 32;
    int q = lane >> 4, l16 = lane & 15;
    f32x4 acc00 = {}, acc01 = {}, acc10 = {}, acc11 = {};
    const u16* ag = Abf + (size_t)(n0 + row)*K3H + chunk*8;
    const u16* bg = Bbf + (size_t)(o0 + row)*K3H + chunk*8;
    int lidx = row*LDA + chunk*8;
    for (int k0 = 0; k0 < K3H; k0 += 32) {
        *(uint4*)&As[lidx] = *(const uint4*)(ag + k0);
        *(uint4*)&Bs[lidx] = *(const uint4*)(bg + k0);
        __syncthreads();
        bf16x8 a0 = *(const bf16x8*)&As[(wr      + l16)*LDA + q*8];
        bf16x8 a1 = *(const bf16x8*)&As[(wr + 16 + l16)*LDA + q*8];
        bf16x8 b0 = *(const bf16x8*)&Bs[(wc      + l16)*LDA + q*8];
        bf16x8 b1 = *(const bf16x8*)&Bs[(wc + 16 + l16)*LDA + q*8];
        acc00 = __builtin_amdgcn_mfma_f32_16x16x32_bf16(a0, b0, acc00, 0,0,0);
        acc01 = __builtin_amdgcn_mfma_f32_16x16x32_bf16(a0, b1, acc01, 0,0,0);
        acc10 = __builtin_amdgcn_mfma_f32_16x16x32_bf16(a1, b0, acc10, 0,0,0);
        acc11 = __builtin_amdgcn_mfma_f32_16x16x32_bf16(a1, b1, acc11, 0,0,0);
        __syncthreads();
    }
    #pragma unroll
    for (int rt = 0; rt < 2; ++rt) {
        #pragma unroll
        for (int ct = 0; ct < 2; ++ct) {
            const f32x4* ac = rt ? (ct ? &acc11 : &acc10) : (ct ? &acc01 : &acc00);
            int o = o0 + wc + ct*16 + l16;
            float bv = bias[o];
            #pragma unroll
            for (int r = 0; r < 4; ++r) {
                int m = n0 + wr + rt*16 + q*4 + r;
                Cbf[(size_t)m*OH + o] = f2bf(fmaxf((*ac)[r] + bv, 0.f));
            }
        }
    }
}

__global__ __launch_bounds__(256) void k_mfma_gemm2(
    const u16* __restrict__ Abf, const u16* __restrict__ Bbf,
    const float* __restrict__ bias, const float* __restrict__ alpha,
    float* __restrict__ out)
{
    int o0 = blockIdx.x * 64;
    int n0 = blockIdx.y * 64;
    int tid = threadIdx.x;
    __shared__ __align__(16) u16 As[64*LDA];
    __shared__ __align__(16) u16 Bs[64*LDA];
    int row = tid >> 2, chunk = tid & 3;
    int wave = tid >> 6, lane = tid & 63;
    int wr = (wave >> 1) * 32, wc = (wave & 1) * 32;
    int q = lane >> 4, l16 = lane & 15;
    f32x4 acc00 = {}, acc01 = {}, acc10 = {}, acc11 = {};
    const u16* ag = Abf + (size_t)(n0 + row)*OH + chunk*8;
    const u16* bg = Bbf + (size_t)(o0 + row)*OH + chunk*8;
    int lidx = row*LDA + chunk*8;
    for (int k0 = 0; k0 < OH; k0 += 32) {
        *(uint4*)&As[lidx] = *(const uint4*)(ag + k0);
        *(uint4*)&Bs[lidx] = *(const uint4*)(bg + k0);
        __syncthreads();
        bf16x8 a0 = *(const bf16x8*)&As[(wr      + l16)*LDA + q*8];
        bf16x8 a1 = *(const bf16x8*)&As[(wr + 16 + l16)*LDA + q*8];
        bf16x8 b0 = *(const bf16x8*)&Bs[(wc      + l16)*LDA + q*8];
        bf16x8 b1 = *(const bf16x8*)&Bs[(wc + 16 + l16)*LDA + q*8];
        acc00 = __builtin_amdgcn_mfma_f32_16x16x32_bf16(a0, b0, acc00, 0,0,0);
        acc01 = __builtin_amdgcn_mfma_f32_16x16x32_bf16(a0, b1, acc01, 0,0,0);
        acc10 = __builtin_amdgcn_mfma_f32_16x16x32_bf16(a1, b0, acc10, 0,0,0);
        acc11 = __builtin_amdgcn_mfma_f32_16x16x32_bf16(a1, b1, acc11, 0,0,0);
        __syncthreads();
    }
    float al = alpha[0];
    #pragma unroll
    for (int rt = 0; rt < 2; ++rt) {
        #pragma unroll
        for (int ct = 0; ct < 2; ++ct) {
            const f32x4* ac = rt ? (ct ? &acc11 : &acc10) : (ct ? &acc01 : &acc00);
            int o = o0 + wc + ct*16 + l16;
            float bv = bias[o];
            #pragma unroll
            for (int r = 0; r < 4; ++r) {
                int m = n0 + wr + rt*16 + q*4 + r;
                out[(size_t)m*HH + o] = al * ((*ac)[r] + bv);
            }
        }
    }
}

// ---------------------------------------------------------------------------
extern "C" void kernel_launch(void* const* d_in, const int* in_sizes, int n_in,
                              void* d_out, int out_size, void* d_ws, size_t ws_size,
                              hipStream_t stream) {
    const float* Hj    = (const float*)d_in[0];
    const float* Hi    = (const float*)d_in[1];
    const float* amask = (const float*)d_in[2];
    const float* pjw   = (const float*)d_in[3];
    const float* piw   = (const float*)d_in[4];
    const float* sw1   = (const float*)d_in[5];
    const float* sb1   = (const float*)d_in[6];
    const float* sw2   = (const float*)d_in[7];
    const float* sb2   = (const float*)d_in[8];
    const float* vw1   = (const float*)d_in[9];
    const float* vb1   = (const float*)d_in[10];
    const float* vw2   = (const float*)d_in[11];
    const float* vb2   = (const float*)d_in[12];
    const float* alpha = (const float*)d_in[13];
    float* out = (float*)d_out;

    float* ws   = (float*)d_ws;
    float* Zj   = ws + OFF_ZJ;
    float* ZIR  = ws + OFF_ZIR;
    float* A    = ws + OFF_A;
    u16* bfbase = (u16*)(ws + F32_END);
    u16* msginb = bfbase + MB_MSGIN;
    u16* h1b    = bfbase + MB_H1;
    u16* w1b    = bfbase + MB_W1;
    u16* w2b    = bfbase + MB_W2;
    u16* probsb = bfbase + MB_PROBS;
    u16* hitb   = bfbase + MB_HIT;
    u16* wsb    = bfbase + MB_WS;

    k_zproj<<<BB*SS, 256, 0, stream>>>(Hj, Hi, pjw, piw, sw1, sb1, Zj, ZIR, A);
    k_prep<<<1, 256, 0, stream>>>(sw1, wsb);
    k_cast_bf<<<(OH*K3H/8 + 255)/256, 256, 0, stream>>>(vw1, w1b, OH*K3H);
    k_cast_bf<<<(HH*OH/8 + 255)/256, 256, 0, stream>>>(vw2, w2b, HH*OH);
    k_hit<<<dim3(SS/32, HH/32, BB), 256, 0, stream>>>(Hi, hitb);
    k_pair_mfma<<<BB*SS, 256, 0, stream>>>(Zj, ZIR, A, wsb, sw2, sb2, amask, probsb);
    k_ctx_mfma<<<dim3(HH/64, SS/64, BB), 256, 0, stream>>>(probsb, hitb, Hj, msginb);
    k_mfma_gemm1<<<dim3(OH/64, BB*SS/64), 256, 0, stream>>>(msginb, w1b, vb1, h1b);
    k_mfma_gemm2<<<dim3(HH/64, BB*SS/64), 256, 0, stream>>>(h1b, w2b, vb2, alpha, out);
}

// Round 4
// 220.879 us; speedup vs baseline: 2.3465x; 1.2112x over previous
//
#include <hip/hip_runtime.h>
#include <hip/hip_bf16.h>
#include <math.h>

#define BB 4
#define SS 512
#define HH 768
#define DD 24
#define MM 96
#define OH 768      // OUT_HID
#define K3H 2304    // 3*H

typedef unsigned short u16;
typedef unsigned int u32;
typedef short bf16x8 __attribute__((ext_vector_type(8)));
typedef float f32x4 __attribute__((ext_vector_type(4)));
typedef u16 u16x4 __attribute__((ext_vector_type(4)));

// fp32 workspace (offsets in floats)
#define OFF_A     0                            // [bs][96]  (Zj.Wa + b1)
#define F32_END   (OFF_A + BB*SS*MM)           // 196608 floats
// bf16 workspace (offsets in u16 from bf16 base)
#define MB_MSGIN  0                            // [2048][2304]
#define MB_H1     (MB_MSGIN + BB*SS*K3H)       // [2048][768]
#define MB_W1     (MB_H1    + BB*SS*OH)        // [768][2304]
#define MB_W2     (MB_W1    + OH*K3H)          // [768][768]
#define MB_PROBS  (MB_W2    + OH*HH)           // [2048][512]
#define MB_HIT    (MB_PROBS + BB*SS*SS)        // [b][768][512]
#define MB_ZJP    (MB_HIT   + BB*HH*SS)        // [2048][32] bf16, cols>=24 zero
#define MB_ZIP    (MB_ZJP   + BB*SS*32)        // [2048][32]
#define MB_WM     (MB_ZIP   + BB*SS*32)        // [96][96] scorer W

__device__ inline u16 f2bf(float x) {
    union { float f; u32 u; } v; v.f = x;
    u32 r = v.u + 0x7fffu + ((v.u >> 16) & 1u);   // RNE
    return (u16)(r >> 16);
}
// pack 2 floats -> bf16x2 (round-half-up: 2 ops/elem)
__device__ inline u32 pk2bf(float lo, float hi) {
    return ((__float_as_uint(lo) + 0x8000u) >> 16) |
           ((__float_as_uint(hi) + 0x8000u) & 0xffff0000u);
}
__device__ inline void unpack8(bf16x8 v, float* f) {
    const u32* d = (const u32*)&v;
    #pragma unroll
    for (int i = 0; i < 4; ++i) {
        f[2*i]   = __uint_as_float(d[i] << 16);
        f[2*i+1] = __uint_as_float(d[i] & 0xffff0000u);
    }
}
// async 16B global->LDS (lane slots must be wave-base + lane*16 -- they are)
__device__ inline void gl_lds16(const u16* g, u16* l) {
    __builtin_amdgcn_global_load_lds(
        (const __attribute__((address_space(1))) void*)g,
        (__attribute__((address_space(3))) void*)l, 16, 0, 0);
}

// ---------------------------------------------------------------------------
// K1: Z projections (fp32 dots) -> Zjp/Zip bf16 [bs][32] (pad zero), A fp32
// ---------------------------------------------------------------------------
__global__ __launch_bounds__(256) void k_zproj(
    const float* __restrict__ Hj, const float* __restrict__ Hi,
    const float* __restrict__ pjw, const float* __restrict__ piw,
    const float* __restrict__ sw1, const float* __restrict__ sb1,
    u16* __restrict__ Zjp, u16* __restrict__ Zip, float* __restrict__ A)
{
    int bs = blockIdx.x;
    __shared__ float hj[HH], hi[HH], zj[DD], zi[DD];
    int tid = threadIdx.x;
    for (int i = tid; i < HH; i += 256) {
        hj[i] = Hj[(size_t)bs*HH + i];
        hi[i] = Hi[(size_t)bs*HH + i];
    }
    __syncthreads();
    int wid = tid >> 6, lane = tid & 63;
    for (int o = wid; o < 2*DD; o += 4) {
        int isJ = (o < DD); int d = isJ ? o : o - DD;
        const float* w = (isJ ? pjw : piw) + (size_t)d * HH;
        const float* x = isJ ? hj : hi;
        float acc = 0.f;
        #pragma unroll
        for (int k = 0; k < HH/64; ++k) { int h = lane + 64*k; acc = fmaf(x[h], w[h], acc); }
        #pragma unroll
        for (int off = 32; off > 0; off >>= 1) acc += __shfl_down(acc, off);
        if (lane == 0) { if (isJ) zj[d] = acc; else zi[d] = acc; }
    }
    __syncthreads();
    if (tid < 32)      Zjp[(size_t)bs*32 + tid] = (tid < DD) ? f2bf(zj[tid]) : (u16)0;
    else if (tid < 64) { int c = tid - 32; Zip[(size_t)bs*32 + c] = (c < DD) ? f2bf(zi[c]) : (u16)0; }
    if (tid < MM) {
        float acc = sb1[tid];
        #pragma unroll
        for (int d = 0; d < DD; ++d) acc = fmaf(zj[d], sw1[tid*96 + d], acc);
        A[(size_t)bs*MM + tid] = acc;
    }
}

// ---------------------------------------------------------------------------
// prep: scorer W-matrix [96][96] bf16.
// cols: [0..23]=Wc  [24..31]=0  [32..55]=Wd  [56..63]=0  [64..87]=Wb
//       [88]=A-slot(0, patched in-reg)  [89..95]=0
// ---------------------------------------------------------------------------
__global__ __launch_bounds__(256) void k_prep(
    const float* __restrict__ sw1, u16* __restrict__ Wm)
{
    for (int i = threadIdx.x; i < MM*96; i += 256) {
        int m = i / 96, k = i % 96;
        float v = 0.f;
        if (k < 24)                 v = sw1[m*96 + 48 + k];         // Wc
        else if (k >= 32 && k < 56) v = sw1[m*96 + 72 + (k - 32)];  // Wd
        else if (k >= 64 && k < 88) v = sw1[m*96 + 24 + (k - 64)];  // Wb
        Wm[i] = f2bf(v);
    }
}

// ---------------------------------------------------------------------------
// K2: register-fragment MFMA pairwise scorer + softmax.
// Block = (b, 4 consecutive s).  D rows = m (a-frag = W), cols = t (b-frag = X).
// X built per-lane in registers from Zjp/Zip; A patched into W k=88, "1" into X.
// ---------------------------------------------------------------------------
__global__ __launch_bounds__(256) void k_pair_mfma(
    const u16* __restrict__ Zjp, const u16* __restrict__ Zip,
    const float* __restrict__ A, const u16* __restrict__ Wm,
    const float* __restrict__ sw2, const float* __restrict__ mask,
    u16* __restrict__ probsb)
{
    int blk = blockIdx.x; int b = blk >> 7; int s0 = (blk & 127) * 4;
    int tid = threadIdx.x, wave = tid >> 6, lane = tid & 63;
    int q = lane >> 4, l16 = lane & 15;
    __shared__ float logits[SS];
    __shared__ float wpart[8];

    // static W a-frags: af[mt][ks] = W[mt*16+l16][ks*32 + q*8 ..+8]
    bf16x8 af[6][3];
    #pragma unroll
    for (int mt = 0; mt < 6; ++mt)
        #pragma unroll
        for (int ks = 0; ks < 3; ++ks)
            af[mt][ks] = *(const bf16x8*)&Wm[(mt*16 + l16)*96 + ks*32 + q*8];
    // w2 per-lane: m = mt*16 + q*4 + r
    float w2v[6][4];
    #pragma unroll
    for (int mt = 0; mt < 6; ++mt)
        #pragma unroll
        for (int r = 0; r < 4; ++r) w2v[mt][r] = sw2[mt*16 + q*4 + r];

    const float NEGF = -3.4028234663852886e38f;

    for (int si = 0; si < 4; ++si) {
        int s = s0 + si; int bs = b*SS + s;
        // zj fragment (broadcast within q-group)
        bf16x8 zjf = *(const bf16x8*)&Zjp[(size_t)bs*32 + q*8];
        float zj[8]; unpack8(zjf, zj);
        // patch A[s][m] into af[mt][2] elem0 for q==3 lanes (k=88)
        #pragma unroll
        for (int mt = 0; mt < 6; ++mt) {
            u32 aval = (u32)f2bf(A[(size_t)bs*MM + mt*16 + l16]);
            u32* dw = (u32*)&af[mt][2];
            dw[0] = (q == 3) ? aval : dw[0];
        }

        for (int tt = wave; tt < 32; tt += 4) {
            int t0 = tt*16;
            bf16x8 zif = *(const bf16x8*)&Zip[((size_t)(b*SS) + t0 + l16)*32 + q*8];
            float zi[8]; unpack8(zif, zi);
            // b2 = Zi fragment; q==3: elem0 = 1.0 (rest already 0 from pad)
            bf16x8 b2 = zif;
            { u32* dw = (u32*)&b2; dw[0] = (q == 3) ? 0x3F80u : dw[0]; }
            bf16x8 b0, b1;
            {
                u32* p0 = (u32*)&b0; u32* p1 = (u32*)&b1;
                #pragma unroll
                for (int i = 0; i < 4; ++i) {
                    p0[i] = pk2bf(zj[2*i]*zi[2*i], zj[2*i+1]*zi[2*i+1]);
                    p1[i] = pk2bf(fabsf(zj[2*i]-zi[2*i]), fabsf(zj[2*i+1]-zi[2*i+1]));
                }
            }
            f32x4 acc[6] = {};
            #pragma unroll
            for (int mt = 0; mt < 6; ++mt) {
                acc[mt] = __builtin_amdgcn_mfma_f32_16x16x32_bf16(af[mt][0], b0, acc[mt], 0,0,0);
                acc[mt] = __builtin_amdgcn_mfma_f32_16x16x32_bf16(af[mt][1], b1, acc[mt], 0,0,0);
                acc[mt] = __builtin_amdgcn_mfma_f32_16x16x32_bf16(af[mt][2], b2, acc[mt], 0,0,0);
            }
            float p = 0.f;
            #pragma unroll
            for (int mt = 0; mt < 6; ++mt)
                #pragma unroll
                for (int r = 0; r < 4; ++r)
                    p = fmaf(fmaxf(acc[mt][r], 0.f), w2v[mt][r], p);
            p += __shfl_xor(p, 16);
            p += __shfl_xor(p, 32);
            if (lane < 16) logits[t0 + lane] = p;
        }
        __syncthreads();
        // softmax over 512
        float l0 = logits[tid]       + (1.f - mask[b*SS + tid])       * NEGF;
        float l1 = logits[tid + 256] + (1.f - mask[b*SS + tid + 256]) * NEGF;
        float mloc = fmaxf(l0, l1);
        #pragma unroll
        for (int off = 32; off > 0; off >>= 1) mloc = fmaxf(mloc, __shfl_xor(mloc, off));
        if (lane == 0) wpart[wave] = mloc;
        __syncthreads();
        float mx = fmaxf(fmaxf(wpart[0], wpart[1]), fmaxf(wpart[2], wpart[3]));
        float e0 = __expf(l0 - mx), e1 = __expf(l1 - mx);
        float sloc = e0 + e1;
        #pragma unroll
        for (int off = 32; off > 0; off >>= 1) sloc += __shfl_xor(sloc, off);
        if (lane == 0) wpart[4 + wave] = sloc;
        __syncthreads();
        float inv = 1.f / (wpart[4] + wpart[5] + wpart[6] + wpart[7]);
        probsb[(size_t)bs*SS + tid]       = f2bf(e0 * inv);
        probsb[(size_t)bs*SS + tid + 256] = f2bf(e1 * inv);
        __syncthreads();
    }
}

// ---------------------------------------------------------------------------
// transpose Hi -> HiT bf16 [b][h][t]
// ---------------------------------------------------------------------------
__global__ __launch_bounds__(256) void k_hit(
    const float* __restrict__ Hi, u16* __restrict__ HiTb)
{
    int b = blockIdx.z; int t0 = blockIdx.x * 32; int h0 = blockIdx.y * 32;
    __shared__ float tile[32][33];
    int tx = threadIdx.x & 31, ty = threadIdx.x >> 5;
    for (int i = ty; i < 32; i += 8)
        tile[i][tx] = Hi[((size_t)(b*SS) + t0 + i)*HH + h0 + tx];
    __syncthreads();
    for (int i = ty; i < 32; i += 8)
        HiTb[((size_t)b*HH + h0 + i)*SS + t0 + tx] = f2bf(tile[tx][i]);
}

// ---------------------------------------------------------------------------
// cast fp32 -> bf16, 8 elements/thread
// ---------------------------------------------------------------------------
__global__ __launch_bounds__(256) void k_cast_bf(
    const float* __restrict__ in, u16* __restrict__ out, int n)
{
    int i = (blockIdx.x*256 + threadIdx.x) * 8;
    if (i >= n) return;
    float4 a = *(const float4*)&in[i];
    float4 b = *(const float4*)&in[i+4];
    u16x4 lo = { f2bf(a.x), f2bf(a.y), f2bf(a.z), f2bf(a.w) };
    u16x4 hi = { f2bf(b.x), f2bf(b.y), f2bf(b.z), f2bf(b.w) };
    *(u16x4*)&out[i]   = lo;
    *(u16x4*)&out[i+4] = hi;
}

// ---------------------------------------------------------------------------
// K3: ctx via MFMA with global_load_lds staging (64x64, BK=32, XOR swizzle),
// fused msg_in epilogue.
// ---------------------------------------------------------------------------
__global__ __launch_bounds__(256) void k_ctx_mfma(
    const u16* __restrict__ probsb, const u16* __restrict__ HiTb,
    const float* __restrict__ Hj, u16* __restrict__ msginb)
{
    int b = blockIdx.z;
    int h0 = blockIdx.x * 64;
    int s0 = blockIdx.y * 64;
    int tid = threadIdx.x;
    __shared__ __align__(16) u16 As[64*32];
    __shared__ __align__(16) u16 Bs[64*32];
    int row = tid >> 2, cs = tid & 3;
    int gchunk = cs ^ ((row >> 1) & 3);
    int wave = tid >> 6, lane = tid & 63;
    int wr = (wave >> 1) * 32, wc = (wave & 1) * 32;
    int q = lane >> 4, l16 = lane & 15;
    int sA = (l16 >> 1) & 3;            // read-side swizzle (rows wr+l16 etc.)
    f32x4 acc00 = {}, acc01 = {}, acc10 = {}, acc11 = {};
    const u16* ag = probsb + ((size_t)(b*SS) + s0 + row)*SS + gchunk*8;
    const u16* bg = HiTb + ((size_t)b*HH + h0 + row)*SS + gchunk*8;
    u16* lA = As + tid*8;
    u16* lB = Bs + tid*8;
    for (int k0 = 0; k0 < SS; k0 += 32) {
        gl_lds16(ag + k0, lA);
        gl_lds16(bg + k0, lB);
        __syncthreads();
        bf16x8 a0 = *(const bf16x8*)&As[(wr      + l16)*32 + (q^sA)*8];
        bf16x8 a1 = *(const bf16x8*)&As[(wr + 16 + l16)*32 + (q^sA)*8];
        bf16x8 b0 = *(const bf16x8*)&Bs[(wc      + l16)*32 + (q^sA)*8];
        bf16x8 b1 = *(const bf16x8*)&Bs[(wc + 16 + l16)*32 + (q^sA)*8];
        acc00 = __builtin_amdgcn_mfma_f32_16x16x32_bf16(a0, b0, acc00, 0,0,0);
        acc01 = __builtin_amdgcn_mfma_f32_16x16x32_bf16(a0, b1, acc01, 0,0,0);
        acc10 = __builtin_amdgcn_mfma_f32_16x16x32_bf16(a1, b0, acc10, 0,0,0);
        acc11 = __builtin_amdgcn_mfma_f32_16x16x32_bf16(a1, b1, acc11, 0,0,0);
        __syncthreads();
    }
    #pragma unroll
    for (int rt = 0; rt < 2; ++rt) {
        #pragma unroll
        for (int ct = 0; ct < 2; ++ct) {
            const f32x4* ac = rt ? (ct ? &acc11 : &acc10) : (ct ? &acc01 : &acc00);
            int h = h0 + wc + ct*16 + l16;
            #pragma unroll
            for (int r = 0; r < 4; ++r) {
                int s = s0 + wr + rt*16 + q*4 + r;
                float v = (*ac)[r];
                float hj = Hj[((size_t)(b*SS) + s)*HH + h];
                u16* mb = msginb + (size_t)(b*SS + s)*K3H + h;
                mb[0]    = f2bf(v);
                mb[HH]   = f2bf(hj);
                mb[2*HH] = f2bf(v * hj);
            }
        }
    }
}

// ---------------------------------------------------------------------------
// G1: h1 = relu(msgin @ w1^T + vb1) -> bf16.  64x64, BK=32, global_load_lds.
// ---------------------------------------------------------------------------
__global__ __launch_bounds__(256) void k_mfma_gemm1(
    const u16* __restrict__ Abf, const u16* __restrict__ Bbf,
    const float* __restrict__ bias, u16* __restrict__ Cbf)
{
    int o0 = blockIdx.x * 64;
    int n0 = blockIdx.y * 64;
    int tid = threadIdx.x;
    __shared__ __align__(16) u16 As[64*32];
    __shared__ __align__(16) u16 Bs[64*32];
    int row = tid >> 2, cs = tid & 3;
    int gchunk = cs ^ ((row >> 1) & 3);
    int wave = tid >> 6, lane = tid & 63;
    int wr = (wave >> 1) * 32, wc = (wave & 1) * 32;
    int q = lane >> 4, l16 = lane & 15;
    int sA = (l16 >> 1) & 3;
    f32x4 acc00 = {}, acc01 = {}, acc10 = {}, acc11 = {};
    const u16* ag = Abf + (size_t)(n0 + row)*K3H + gchunk*8;
    const u16* bg = Bbf + (size_t)(o0 + row)*K3H + gchunk*8;
    u16* lA = As + tid*8;
    u16* lB = Bs + tid*8;
    for (int k0 = 0; k0 < K3H; k0 += 32) {
        gl_lds16(ag + k0, lA);
        gl_lds16(bg + k0, lB);
        __syncthreads();
        bf16x8 a0 = *(const bf16x8*)&As[(wr      + l16)*32 + (q^sA)*8];
        bf16x8 a1 = *(const bf16x8*)&As[(wr + 16 + l16)*32 + (q^sA)*8];
        bf16x8 b0 = *(const bf16x8*)&Bs[(wc      + l16)*32 + (q^sA)*8];
        bf16x8 b1 = *(const bf16x8*)&Bs[(wc + 16 + l16)*32 + (q^sA)*8];
        acc00 = __builtin_amdgcn_mfma_f32_16x16x32_bf16(a0, b0, acc00, 0,0,0);
        acc01 = __builtin_amdgcn_mfma_f32_16x16x32_bf16(a0, b1, acc01, 0,0,0);
        acc10 = __builtin_amdgcn_mfma_f32_16x16x32_bf16(a1, b0, acc10, 0,0,0);
        acc11 = __builtin_amdgcn_mfma_f32_16x16x32_bf16(a1, b1, acc11, 0,0,0);
        __syncthreads();
    }
    #pragma unroll
    for (int rt = 0; rt < 2; ++rt) {
        #pragma unroll
        for (int ct = 0; ct < 2; ++ct) {
            const f32x4* ac = rt ? (ct ? &acc11 : &acc10) : (ct ? &acc01 : &acc00);
            int o = o0 + wc + ct*16 + l16;
            float bv = bias[o];
            #pragma unroll
            for (int r = 0; r < 4; ++r) {
                int m = n0 + wr + rt*16 + q*4 + r;
                Cbf[(size_t)m*OH + o] = f2bf(fmaxf((*ac)[r] + bv, 0.f));
            }
        }
    }
}

// ---------------------------------------------------------------------------
// G2: out = alpha * (h1 @ w2^T + vb2).  64x64, BK=32, global_load_lds.
// ---------------------------------------------------------------------------
__global__ __launch_bounds__(256) void k_mfma_gemm2(
    const u16* __restrict__ Abf, const u16* __restrict__ Bbf,
    const float* __restrict__ bias, const float* __restrict__ alpha,
    float* __restrict__ out)
{
    int o0 = blockIdx.x * 64;
    int n0 = blockIdx.y * 64;
    int tid = threadIdx.x;
    __shared__ __align__(16) u16 As[64*32];
    __shared__ __align__(16) u16 Bs[64*32];
    int row = tid >> 2, cs = tid & 3;
    int gchunk = cs ^ ((row >> 1) & 3);
    int wave = tid >> 6, lane = tid & 63;
    int wr = (wave >> 1) * 32, wc = (wave & 1) * 32;
    int q = lane >> 4, l16 = lane & 15;
    int sA = (l16 >> 1) & 3;
    f32x4 acc00 = {}, acc01 = {}, acc10 = {}, acc11 = {};
    const u16* ag = Abf + (size_t)(n0 + row)*OH + gchunk*8;
    const u16* bg = Bbf + (size_t)(o0 + row)*OH + gchunk*8;
    u16* lA = As + tid*8;
    u16* lB = Bs + tid*8;
    for (int k0 = 0; k0 < OH; k0 += 32) {
        gl_lds16(ag + k0, lA);
        gl_lds16(bg + k0, lB);
        __syncthreads();
        bf16x8 a0 = *(const bf16x8*)&As[(wr      + l16)*32 + (q^sA)*8];
        bf16x8 a1 = *(const bf16x8*)&As[(wr + 16 + l16)*32 + (q^sA)*8];
        bf16x8 b0 = *(const bf16x8*)&Bs[(wc      + l16)*32 + (q^sA)*8];
        bf16x8 b1 = *(const bf16x8*)&Bs[(wc + 16 + l16)*32 + (q^sA)*8];
        acc00 = __builtin_amdgcn_mfma_f32_16x16x32_bf16(a0, b0, acc00, 0,0,0);
        acc01 = __builtin_amdgcn_mfma_f32_16x16x32_bf16(a0, b1, acc01, 0,0,0);
        acc10 = __builtin_amdgcn_mfma_f32_16x16x32_bf16(a1, b0, acc10, 0,0,0);
        acc11 = __builtin_amdgcn_mfma_f32_16x16x32_bf16(a1, b1, acc11, 0,0,0);
        __syncthreads();
    }
    float al = alpha[0];
    #pragma unroll
    for (int rt = 0; rt < 2; ++rt) {
        #pragma unroll
        for (int ct = 0; ct < 2; ++ct) {
            const f32x4* ac = rt ? (ct ? &acc11 : &acc10) : (ct ? &acc01 : &acc00);
            int o = o0 + wc + ct*16 + l16;
            float bv = bias[o];
            #pragma unroll
            for (int r = 0; r < 4; ++r) {
                int m = n0 + wr + rt*16 + q*4 + r;
                out[(size_t)m*HH + o] = al * ((*ac)[r] + bv);
            }
        }
    }
}

// ---------------------------------------------------------------------------
extern "C" void kernel_launch(void* const* d_in, const int* in_sizes, int n_in,
                              void* d_out, int out_size, void* d_ws, size_t ws_size,
                              hipStream_t stream) {
    const float* Hj    = (const float*)d_in[0];
    const float* Hi    = (const float*)d_in[1];
    const float* amask = (const float*)d_in[2];
    const float* pjw   = (const float*)d_in[3];
    const float* piw   = (const float*)d_in[4];
    const float* sw1   = (const float*)d_in[5];
    const float* sb1   = (const float*)d_in[6];
    const float* sw2   = (const float*)d_in[7];
    const float* sb2   = (const float*)d_in[8];
    const float* vw1   = (const float*)d_in[9];
    const float* vb1   = (const float*)d_in[10];
    const float* vw2   = (const float*)d_in[11];
    const float* vb2   = (const float*)d_in[12];
    const float* alpha = (const float*)d_in[13];
    float* out = (float*)d_out;
    (void)sb2; // softmax is shift-invariant; sb2 cancels

    float* ws   = (float*)d_ws;
    float* A    = ws + OFF_A;
    u16* bfbase = (u16*)(ws + F32_END);
    u16* msginb = bfbase + MB_MSGIN;
    u16* h1b    = bfbase + MB_H1;
    u16* w1b    = bfbase + MB_W1;
    u16* w2b    = bfbase + MB_W2;
    u16* probsb = bfbase + MB_PROBS;
    u16* hitb   = bfbase + MB_HIT;
    u16* zjp    = bfbase + MB_ZJP;
    u16* zip    = bfbase + MB_ZIP;
    u16* wm     = bfbase + MB_WM;

    k_zproj<<<BB*SS, 256, 0, stream>>>(Hj, Hi, pjw, piw, sw1, sb1, zjp, zip, A);
    k_prep<<<1, 256, 0, stream>>>(sw1, wm);
    k_cast_bf<<<(OH*K3H/8 + 255)/256, 256, 0, stream>>>(vw1, w1b, OH*K3H);
    k_cast_bf<<<(HH*OH/8 + 255)/256, 256, 0, stream>>>(vw2, w2b, HH*OH);
    k_hit<<<dim3(SS/32, HH/32, BB), 256, 0, stream>>>(Hi, hitb);
    k_pair_mfma<<<BB*SS/4, 256, 0, stream>>>(zjp, zip, A, wm, sw2, amask, probsb);
    k_ctx_mfma<<<dim3(HH/64, SS/64, BB), 256, 0, stream>>>(probsb, hitb, Hj, msginb);
    k_mfma_gemm1<<<dim3(OH/64, BB*SS/64), 256, 0, stream>>>(msginb, w1b, vb1, h1b);
    k_mfma_gemm2<<<dim3(HH/64, BB*SS/64), 256, 0, stream>>>(h1b, w2b, vb2, alpha, out);
}

// Round 5
// 204.066 us; speedup vs baseline: 2.5399x; 1.0824x over previous
//
#include <hip/hip_runtime.h>
#include <hip/hip_bf16.h>
#include <math.h>

#define BB 4
#define SS 512
#define HH 768
#define DD 24
#define MM 96
#define OH 768      // OUT_HID
#define K3H 2304    // 3*H

typedef unsigned short u16;
typedef unsigned int u32;
typedef short bf16x8 __attribute__((ext_vector_type(8)));
typedef float f32x4 __attribute__((ext_vector_type(4)));
typedef u16 u16x4 __attribute__((ext_vector_type(4)));

// fp32 workspace (offsets in floats)
#define OFF_A     0                            // [bs][96]  (Zj.Wa + b1)
#define F32_END   (OFF_A + BB*SS*MM)           // 196608 floats
// bf16 workspace (offsets in u16 from bf16 base)
#define MB_MSGIN  0                            // [2048][2304]
#define MB_H1     (MB_MSGIN + BB*SS*K3H)       // [2048][768]
#define MB_W1     (MB_H1    + BB*SS*OH)        // [768][2304]
#define MB_W2     (MB_W1    + OH*K3H)          // [768][768]
#define MB_PROBS  (MB_W2    + OH*HH)           // [2048][512]
#define MB_HIT    (MB_PROBS + BB*SS*SS)        // [b][768][512]
#define MB_ZJP    (MB_HIT   + BB*HH*SS)        // [2048][32] bf16, cols>=24 zero
#define MB_ZIP    (MB_ZJP   + BB*SS*32)        // [2048][32]
#define MB_WM     (MB_ZIP   + BB*SS*32)        // [96][96] scorer W

__device__ inline u16 f2bf(float x) {
    union { float f; u32 u; } v; v.f = x;
    u32 r = v.u + 0x7fffu + ((v.u >> 16) & 1u);   // RNE
    return (u16)(r >> 16);
}
// pack 2 floats -> bf16x2 (round-half-up)
__device__ inline u32 pk2bf(float lo, float hi) {
    return ((__float_as_uint(lo) + 0x8000u) >> 16) |
           ((__float_as_uint(hi) + 0x8000u) & 0xffff0000u);
}
__device__ inline void unpack8(bf16x8 v, float* f) {
    const u32* d = (const u32*)&v;
    #pragma unroll
    for (int i = 0; i < 4; ++i) {
        f[2*i]   = __uint_as_float(d[i] << 16);
        f[2*i+1] = __uint_as_float(d[i] & 0xffff0000u);
    }
}
// async 16B global->LDS (lane slots must be wave-base + lane*16 -- they are)
__device__ inline void gl_lds16(const u16* g, u16* l) {
    __builtin_amdgcn_global_load_lds(
        (const __attribute__((address_space(1))) void*)g,
        (__attribute__((address_space(3))) void*)l, 16, 0, 0);
}

// ---------------------------------------------------------------------------
// K1: Z projections (fp32 dots) -> Zjp/Zip bf16 [bs][32] (pad zero), A fp32
// ---------------------------------------------------------------------------
__global__ __launch_bounds__(256) void k_zproj(
    const float* __restrict__ Hj, const float* __restrict__ Hi,
    const float* __restrict__ pjw, const float* __restrict__ piw,
    const float* __restrict__ sw1, const float* __restrict__ sb1,
    u16* __restrict__ Zjp, u16* __restrict__ Zip, float* __restrict__ A)
{
    int bs = blockIdx.x;
    __shared__ float hj[HH], hi[HH], zj[DD], zi[DD];
    int tid = threadIdx.x;
    for (int i = tid; i < HH; i += 256) {
        hj[i] = Hj[(size_t)bs*HH + i];
        hi[i] = Hi[(size_t)bs*HH + i];
    }
    __syncthreads();
    int wid = tid >> 6, lane = tid & 63;
    for (int o = wid; o < 2*DD; o += 4) {
        int isJ = (o < DD); int d = isJ ? o : o - DD;
        const float* w = (isJ ? pjw : piw) + (size_t)d * HH;
        const float* x = isJ ? hj : hi;
        float acc = 0.f;
        #pragma unroll
        for (int k = 0; k < HH/64; ++k) { int h = lane + 64*k; acc = fmaf(x[h], w[h], acc); }
        #pragma unroll
        for (int off = 32; off > 0; off >>= 1) acc += __shfl_down(acc, off);
        if (lane == 0) { if (isJ) zj[d] = acc; else zi[d] = acc; }
    }
    __syncthreads();
    if (tid < 32)      Zjp[(size_t)bs*32 + tid] = (tid < DD) ? f2bf(zj[tid]) : (u16)0;
    else if (tid < 64) { int c = tid - 32; Zip[(size_t)bs*32 + c] = (c < DD) ? f2bf(zi[c]) : (u16)0; }
    if (tid < MM) {
        float acc = sb1[tid];
        #pragma unroll
        for (int d = 0; d < DD; ++d) acc = fmaf(zj[d], sw1[tid*96 + d], acc);
        A[(size_t)bs*MM + tid] = acc;
    }
}

// ---------------------------------------------------------------------------
// fused weight prep: block 0 builds scorer Wm [96][96]
//   cols [0..23]=Wc [24..31]=0 [32..55]=Wd [56..63]=0 [64..87]=Wb [88..95]=0
// blocks 1..864 cast vw1, blocks 865..1152 cast vw2
// ---------------------------------------------------------------------------
__global__ __launch_bounds__(256) void k_wprep(
    const float* __restrict__ sw1, const float* __restrict__ vw1,
    const float* __restrict__ vw2,
    u16* __restrict__ Wm, u16* __restrict__ w1b, u16* __restrict__ w2b)
{
    int bx = blockIdx.x;
    if (bx == 0) {
        for (int i = threadIdx.x; i < MM*96; i += 256) {
            int m = i / 96, k = i % 96;
            float v = 0.f;
            if (k < 24)                 v = sw1[m*96 + 48 + k];         // Wc
            else if (k >= 32 && k < 56) v = sw1[m*96 + 72 + (k - 32)];  // Wd
            else if (k >= 64 && k < 88) v = sw1[m*96 + 24 + (k - 64)];  // Wb
            Wm[i] = f2bf(v);
        }
        return;
    }
    int idx = bx - 1;
    const float* src; u16* dst;
    if (idx < 864) { src = vw1; dst = w1b; }
    else           { idx -= 864; src = vw2; dst = w2b; }
    int i = (idx*256 + threadIdx.x) * 8;
    float4 a = *(const float4*)&src[i];
    float4 c = *(const float4*)&src[i+4];
    u16x4 lo = { f2bf(a.x), f2bf(a.y), f2bf(a.z), f2bf(a.w) };
    u16x4 hi = { f2bf(c.x), f2bf(c.y), f2bf(c.z), f2bf(c.w) };
    *(u16x4*)&dst[i]   = lo;
    *(u16x4*)&dst[i+4] = hi;
}

// ---------------------------------------------------------------------------
// K2: register-fragment MFMA pairwise scorer + softmax.
// Block = (b, 2 s) x 2 t-halves; 4 waves; wave = (si = w&1, half = w>>1).
// Per wave: afc[m][k] = bf16(zj_k*Wc + Wb) (+A in 1-column), afd = Wd.
// Inner tile: 12 MFMA, b-frags = raw zi frag (+1 patch) and |zj-zi|.
// Zi staged block-wide in LDS via global_load_lds with XOR chunk swizzle.
// ---------------------------------------------------------------------------
__global__ __launch_bounds__(256) void k_pair_mfma(
    const u16* __restrict__ Zjp, const u16* __restrict__ Zip,
    const float* __restrict__ A, const u16* __restrict__ Wm,
    const float* __restrict__ sw2, const float* __restrict__ mask,
    u16* __restrict__ probsb)
{
    int blk = blockIdx.x; int b = blk >> 8; int s0 = (blk & 255) * 2;
    int tid = threadIdx.x, wave = tid >> 6, lane = tid & 63;
    int q = lane >> 4, l16 = lane & 15;
    int si = wave & 1, half = wave >> 1;
    int s = s0 + si, bs = b*SS + s;
    __shared__ __align__(16) u16 ZiS[SS*32];      // 32 KB, chunk-swizzled
    __shared__ float logits[2][SS];               // 4 KB

    // ---- cooperative staging of all 512 zi rows for this b (8 x 4KB)
    {
        const u16* zb = Zip + (size_t)b*SS*32;
        #pragma unroll
        for (int p = 0; p < 8; ++p) {
            int idx = p*256 + tid;                // 16B-granule id
            int t = idx >> 2, c = idx & 3;
            int g = c ^ ((t + (t >> 2)) & 3);
            gl_lds16(zb + t*32 + g*8, ZiS + idx*8);
        }
    }

    // ---- per-wave setup (overlaps staging latency)
    bf16x8 zjf = *(const bf16x8*)&Zjp[(size_t)bs*32 + q*8];
    float zj[8]; unpack8(zjf, zj);
    bf16x8 afc[6], afd[6];
    #pragma unroll
    for (int mt = 0; mt < 6; ++mt) {
        const u16* wrow = &Wm[(mt*16 + l16)*96];
        bf16x8 wcf = *(const bf16x8*)&wrow[q*8];
        afd[mt]    = *(const bf16x8*)&wrow[32 + q*8];
        bf16x8 wbf = *(const bf16x8*)&wrow[64 + q*8];
        float fc[8], fb[8];
        unpack8(wcf, fc); unpack8(wbf, fb);
        u32 aval = (u32)f2bf(A[(size_t)bs*MM + mt*16 + l16]);
        union { u32 d[4]; bf16x8 v; } pk;
        #pragma unroll
        for (int i = 0; i < 4; ++i)
            pk.d[i] = pk2bf(fmaf(fc[2*i], zj[2*i], fb[2*i]),
                            fmaf(fc[2*i+1], zj[2*i+1], fb[2*i+1]));
        pk.d[0] = (q == 3) ? aval : pk.d[0];
        afc[mt] = pk.v;
    }
    float w2v[6][4];
    #pragma unroll
    for (int mt = 0; mt < 6; ++mt)
        #pragma unroll
        for (int r = 0; r < 4; ++r) w2v[mt][r] = sw2[mt*16 + q*4 + r];

    __syncthreads();   // staging complete

    // ---- 16 t-tiles per wave
    for (int k = 0; k < 16; ++k) {
        int t0 = (half*16 + k) * 16;
        int trow = t0 + l16;
        int sw = q ^ ((trow + (trow >> 2)) & 3);
        bf16x8 zif = *(const bf16x8*)&ZiS[trow*32 + sw*8];
        float zi[8]; unpack8(zif, zi);
        union { u32 d[4]; bf16x8 v; } b1, b2;
        #pragma unroll
        for (int i = 0; i < 4; ++i)
            b1.d[i] = pk2bf(fabsf(zj[2*i] - zi[2*i]), fabsf(zj[2*i+1] - zi[2*i+1]));
        b2.v = zif;
        b2.d[0] = (q == 3) ? 0x3F80u : b2.d[0];
        f32x4 acc[6];
        #pragma unroll
        for (int mt = 0; mt < 6; ++mt) {
            f32x4 a = {};
            a = __builtin_amdgcn_mfma_f32_16x16x32_bf16(afc[mt], b2.v, a, 0,0,0);
            a = __builtin_amdgcn_mfma_f32_16x16x32_bf16(afd[mt], b1.v, a, 0,0,0);
            acc[mt] = a;
        }
        float p = 0.f;
        #pragma unroll
        for (int mt = 0; mt < 6; ++mt)
            #pragma unroll
            for (int r = 0; r < 4; ++r)
                p = fmaf(fmaxf(acc[mt][r], 0.f), w2v[mt][r], p);
        p += __shfl_xor(p, 16);
        p += __shfl_xor(p, 32);
        if (lane < 16) logits[si][t0 + lane] = p;
    }
    __syncthreads();

    // ---- softmax: wave w<2 handles s0+w, pure shuffle reduce
    if (wave < 2) {
        const float NEGF = -3.4028234663852886e38f;
        int bss = b*SS + s0 + wave;
        float l[8], e[8];
        float mx = -INFINITY;
        #pragma unroll
        for (int i = 0; i < 8; ++i) {
            int idx = lane + i*64;
            l[i] = logits[wave][idx] + (1.f - mask[b*SS + idx]) * NEGF;
            mx = fmaxf(mx, l[i]);
        }
        #pragma unroll
        for (int off = 32; off > 0; off >>= 1) mx = fmaxf(mx, __shfl_xor(mx, off));
        float sum = 0.f;
        #pragma unroll
        for (int i = 0; i < 8; ++i) { e[i] = __expf(l[i] - mx); sum += e[i]; }
        #pragma unroll
        for (int off = 32; off > 0; off >>= 1) sum += __shfl_xor(sum, off);
        float inv = 1.f / sum;
        #pragma unroll
        for (int i = 0; i < 8; ++i)
            probsb[(size_t)bss*SS + lane + i*64] = f2bf(e[i] * inv);
    }
}

// ---------------------------------------------------------------------------
// transpose Hi -> HiT bf16 [b][h][t]
// ---------------------------------------------------------------------------
__global__ __launch_bounds__(256) void k_hit(
    const float* __restrict__ Hi, u16* __restrict__ HiTb)
{
    int b = blockIdx.z; int t0 = blockIdx.x * 32; int h0 = blockIdx.y * 32;
    __shared__ float tile[32][33];
    int tx = threadIdx.x & 31, ty = threadIdx.x >> 5;
    for (int i = ty; i < 32; i += 8)
        tile[i][tx] = Hi[((size_t)(b*SS) + t0 + i)*HH + h0 + tx];
    __syncthreads();
    for (int i = ty; i < 32; i += 8)
        HiTb[((size_t)b*HH + h0 + i)*SS + t0 + tx] = f2bf(tile[tx][i]);
}

// ---------------------------------------------------------------------------
// K3: ctx via MFMA with global_load_lds staging (64x64, BK=32, XOR swizzle),
// fused msg_in epilogue.
// ---------------------------------------------------------------------------
__global__ __launch_bounds__(256) void k_ctx_mfma(
    const u16* __restrict__ probsb, const u16* __restrict__ HiTb,
    const float* __restrict__ Hj, u16* __restrict__ msginb)
{
    int b = blockIdx.z;
    int h0 = blockIdx.x * 64;
    int s0 = blockIdx.y * 64;
    int tid = threadIdx.x;
    __shared__ __align__(16) u16 As[64*32];
    __shared__ __align__(16) u16 Bs[64*32];
    int row = tid >> 2, cs = tid & 3;
    int gchunk = cs ^ ((row >> 1) & 3);
    int wave = tid >> 6, lane = tid & 63;
    int wr = (wave >> 1) * 32, wc = (wave & 1) * 32;
    int q = lane >> 4, l16 = lane & 15;
    int sA = (l16 >> 1) & 3;
    f32x4 acc00 = {}, acc01 = {}, acc10 = {}, acc11 = {};
    const u16* ag = probsb + ((size_t)(b*SS) + s0 + row)*SS + gchunk*8;
    const u16* bg = HiTb + ((size_t)b*HH + h0 + row)*SS + gchunk*8;
    u16* lA = As + tid*8;
    u16* lB = Bs + tid*8;
    for (int k0 = 0; k0 < SS; k0 += 32) {
        gl_lds16(ag + k0, lA);
        gl_lds16(bg + k0, lB);
        __syncthreads();
        bf16x8 a0 = *(const bf16x8*)&As[(wr      + l16)*32 + (q^sA)*8];
        bf16x8 a1 = *(const bf16x8*)&As[(wr + 16 + l16)*32 + (q^sA)*8];
        bf16x8 b0 = *(const bf16x8*)&Bs[(wc      + l16)*32 + (q^sA)*8];
        bf16x8 b1 = *(const bf16x8*)&Bs[(wc + 16 + l16)*32 + (q^sA)*8];
        acc00 = __builtin_amdgcn_mfma_f32_16x16x32_bf16(a0, b0, acc00, 0,0,0);
        acc01 = __builtin_amdgcn_mfma_f32_16x16x32_bf16(a0, b1, acc01, 0,0,0);
        acc10 = __builtin_amdgcn_mfma_f32_16x16x32_bf16(a1, b0, acc10, 0,0,0);
        acc11 = __builtin_amdgcn_mfma_f32_16x16x32_bf16(a1, b1, acc11, 0,0,0);
        __syncthreads();
    }
    #pragma unroll
    for (int rt = 0; rt < 2; ++rt) {
        #pragma unroll
        for (int ct = 0; ct < 2; ++ct) {
            const f32x4* ac = rt ? (ct ? &acc11 : &acc10) : (ct ? &acc01 : &acc00);
            int h = h0 + wc + ct*16 + l16;
            #pragma unroll
            for (int r = 0; r < 4; ++r) {
                int s = s0 + wr + rt*16 + q*4 + r;
                float v = (*ac)[r];
                float hj = Hj[((size_t)(b*SS) + s)*HH + h];
                u16* mb = msginb + (size_t)(b*SS + s)*K3H + h;
                mb[0]    = f2bf(v);
                mb[HH]   = f2bf(hj);
                mb[2*HH] = f2bf(v * hj);
            }
        }
    }
}

// ---------------------------------------------------------------------------
// G1: h1 = relu(msgin @ w1^T + vb1) -> bf16.  64x64, BK=32, global_load_lds.
// ---------------------------------------------------------------------------
__global__ __launch_bounds__(256) void k_mfma_gemm1(
    const u16* __restrict__ Abf, const u16* __restrict__ Bbf,
    const float* __restrict__ bias, u16* __restrict__ Cbf)
{
    int o0 = blockIdx.x * 64;
    int n0 = blockIdx.y * 64;
    int tid = threadIdx.x;
    __shared__ __align__(16) u16 As[64*32];
    __shared__ __align__(16) u16 Bs[64*32];
    int row = tid >> 2, cs = tid & 3;
    int gchunk = cs ^ ((row >> 1) & 3);
    int wave = tid >> 6, lane = tid & 63;
    int wr = (wave >> 1) * 32, wc = (wave & 1) * 32;
    int q = lane >> 4, l16 = lane & 15;
    int sA = (l16 >> 1) & 3;
    f32x4 acc00 = {}, acc01 = {}, acc10 = {}, acc11 = {};
    const u16* ag = Abf + (size_t)(n0 + row)*K3H + gchunk*8;
    const u16* bg = Bbf + (size_t)(o0 + row)*K3H + gchunk*8;
    u16* lA = As + tid*8;
    u16* lB = Bs + tid*8;
    for (int k0 = 0; k0 < K3H; k0 += 32) {
        gl_lds16(ag + k0, lA);
        gl_lds16(bg + k0, lB);
        __syncthreads();
        bf16x8 a0 = *(const bf16x8*)&As[(wr      + l16)*32 + (q^sA)*8];
        bf16x8 a1 = *(const bf16x8*)&As[(wr + 16 + l16)*32 + (q^sA)*8];
        bf16x8 b0 = *(const bf16x8*)&Bs[(wc      + l16)*32 + (q^sA)*8];
        bf16x8 b1 = *(const bf16x8*)&Bs[(wc + 16 + l16)*32 + (q^sA)*8];
        acc00 = __builtin_amdgcn_mfma_f32_16x16x32_bf16(a0, b0, acc00, 0,0,0);
        acc01 = __builtin_amdgcn_mfma_f32_16x16x32_bf16(a0, b1, acc01, 0,0,0);
        acc10 = __builtin_amdgcn_mfma_f32_16x16x32_bf16(a1, b0, acc10, 0,0,0);
        acc11 = __builtin_amdgcn_mfma_f32_16x16x32_bf16(a1, b1, acc11, 0,0,0);
        __syncthreads();
    }
    #pragma unroll
    for (int rt = 0; rt < 2; ++rt) {
        #pragma unroll
        for (int ct = 0; ct < 2; ++ct) {
            const f32x4* ac = rt ? (ct ? &acc11 : &acc10) : (ct ? &acc01 : &acc00);
            int o = o0 + wc + ct*16 + l16;
            float bv = bias[o];
            #pragma unroll
            for (int r = 0; r < 4; ++r) {
                int m = n0 + wr + rt*16 + q*4 + r;
                Cbf[(size_t)m*OH + o] = f2bf(fmaxf((*ac)[r] + bv, 0.f));
            }
        }
    }
}

// ---------------------------------------------------------------------------
// G2: out = alpha * (h1 @ w2^T + vb2).  64x64, BK=32, global_load_lds.
// ---------------------------------------------------------------------------
__global__ __launch_bounds__(256) void k_mfma_gemm2(
    const u16* __restrict__ Abf, const u16* __restrict__ Bbf,
    const float* __restrict__ bias, const float* __restrict__ alpha,
    float* __restrict__ out)
{
    int o0 = blockIdx.x * 64;
    int n0 = blockIdx.y * 64;
    int tid = threadIdx.x;
    __shared__ __align__(16) u16 As[64*32];
    __shared__ __align__(16) u16 Bs[64*32];
    int row = tid >> 2, cs = tid & 3;
    int gchunk = cs ^ ((row >> 1) & 3);
    int wave = tid >> 6, lane = tid & 63;
    int wr = (wave >> 1) * 32, wc = (wave & 1) * 32;
    int q = lane >> 4, l16 = lane & 15;
    int sA = (l16 >> 1) & 3;
    f32x4 acc00 = {}, acc01 = {}, acc10 = {}, acc11 = {};
    const u16* ag = Abf + (size_t)(n0 + row)*OH + gchunk*8;
    const u16* bg = Bbf + (size_t)(o0 + row)*OH + gchunk*8;
    u16* lA = As + tid*8;
    u16* lB = Bs + tid*8;
    for (int k0 = 0; k0 < OH; k0 += 32) {
        gl_lds16(ag + k0, lA);
        gl_lds16(bg + k0, lB);
        __syncthreads();
        bf16x8 a0 = *(const bf16x8*)&As[(wr      + l16)*32 + (q^sA)*8];
        bf16x8 a1 = *(const bf16x8*)&As[(wr + 16 + l16)*32 + (q^sA)*8];
        bf16x8 b0 = *(const bf16x8*)&Bs[(wc      + l16)*32 + (q^sA)*8];
        bf16x8 b1 = *(const bf16x8*)&Bs[(wc + 16 + l16)*32 + (q^sA)*8];
        acc00 = __builtin_amdgcn_mfma_f32_16x16x32_bf16(a0, b0, acc00, 0,0,0);
        acc01 = __builtin_amdgcn_mfma_f32_16x16x32_bf16(a0, b1, acc01, 0,0,0);
        acc10 = __builtin_amdgcn_mfma_f32_16x16x32_bf16(a1, b0, acc10, 0,0,0);
        acc11 = __builtin_amdgcn_mfma_f32_16x16x32_bf16(a1, b1, acc11, 0,0,0);
        __syncthreads();
    }
    float al = alpha[0];
    #pragma unroll
    for (int rt = 0; rt < 2; ++rt) {
        #pragma unroll
        for (int ct = 0; ct < 2; ++ct) {
            const f32x4* ac = rt ? (ct ? &acc11 : &acc10) : (ct ? &acc01 : &acc00);
            int o = o0 + wc + ct*16 + l16;
            float bv = bias[o];
            #pragma unroll
            for (int r = 0; r < 4; ++r) {
                int m = n0 + wr + rt*16 + q*4 + r;
                out[(size_t)m*HH + o] = al * ((*ac)[r] + bv);
            }
        }
    }
}

// ---------------------------------------------------------------------------
extern "C" void kernel_launch(void* const* d_in, const int* in_sizes, int n_in,
                              void* d_out, int out_size, void* d_ws, size_t ws_size,
                              hipStream_t stream) {
    const float* Hj    = (const float*)d_in[0];
    const float* Hi    = (const float*)d_in[1];
    const float* amask = (const float*)d_in[2];
    const float* pjw   = (const float*)d_in[3];
    const float* piw   = (const float*)d_in[4];
    const float* sw1   = (const float*)d_in[5];
    const float* sb1   = (const float*)d_in[6];
    const float* sw2   = (const float*)d_in[7];
    const float* sb2   = (const float*)d_in[8];
    const float* vw1   = (const float*)d_in[9];
    const float* vb1   = (const float*)d_in[10];
    const float* vw2   = (const float*)d_in[11];
    const float* vb2   = (const float*)d_in[12];
    const float* alpha = (const float*)d_in[13];
    float* out = (float*)d_out;
    (void)sb2; // softmax is shift-invariant; sb2 cancels

    float* ws   = (float*)d_ws;
    float* A    = ws + OFF_A;
    u16* bfbase = (u16*)(ws + F32_END);
    u16* msginb = bfbase + MB_MSGIN;
    u16* h1b    = bfbase + MB_H1;
    u16* w1b    = bfbase + MB_W1;
    u16* w2b    = bfbase + MB_W2;
    u16* probsb = bfbase + MB_PROBS;
    u16* hitb   = bfbase + MB_HIT;
    u16* zjp    = bfbase + MB_ZJP;
    u16* zip    = bfbase + MB_ZIP;
    u16* wm     = bfbase + MB_WM;

    k_zproj<<<BB*SS, 256, 0, stream>>>(Hj, Hi, pjw, piw, sw1, sb1, zjp, zip, A);
    k_wprep<<<1 + 864 + 288, 256, 0, stream>>>(sw1, vw1, vw2, wm, w1b, w2b);
    k_hit<<<dim3(SS/32, HH/32, BB), 256, 0, stream>>>(Hi, hitb);
    k_pair_mfma<<<BB*SS/2, 256, 0, stream>>>(zjp, zip, A, wm, sw2, amask, probsb);
    k_ctx_mfma<<<dim3(HH/64, SS/64, BB), 256, 0, stream>>>(probsb, hitb, Hj, msginb);
    k_mfma_gemm1<<<dim3(OH/64, BB*SS/64), 256, 0, stream>>>(msginb, w1b, vb1, h1b);
    k_mfma_gemm2<<<dim3(HH/64, BB*SS/64), 256, 0, stream>>>(h1b, w2b, vb2, alpha, out);
}

// Round 6
// 194.464 us; speedup vs baseline: 2.6653x; 1.0494x over previous
//
#include <hip/hip_runtime.h>
#include <hip/hip_bf16.h>
#include <math.h>

#define BB 4
#define SS 512
#define HH 768
#define DD 24
#define MM 96
#define OH 768      // OUT_HID
#define K3H 2304    // 3*H

typedef unsigned short u16;
typedef unsigned int u32;
typedef short bf16x8 __attribute__((ext_vector_type(8)));
typedef float f32x4 __attribute__((ext_vector_type(4)));
typedef u16 u16x4 __attribute__((ext_vector_type(4)));

// bf16 workspace (offsets in u16 from ws base)
#define MB_MSGIN  0                            // [2048][2304]
#define MB_H1     (MB_MSGIN + BB*SS*K3H)       // [2048][768]
#define MB_W1     (MB_H1    + BB*SS*OH)        // [768][2304]
#define MB_W2     (MB_W1    + OH*K3H)          // [768][768]
#define MB_PROBS  (MB_W2    + OH*HH)           // [2048][512]
#define MB_HIT    (MB_PROBS + BB*SS*SS)        // [b][768][512]
#define MB_ZJP    (MB_HIT   + BB*HH*SS)        // [2048][32] bf16, cols>=24 zero
#define MB_ZIP    (MB_ZJP   + BB*SS*32)        // [2048][32]
#define MB_WM     (MB_ZIP   + BB*SS*32)        // [96][96] scorer W
#define MB_WAB    (MB_WM    + MM*96)           // [96][32]  Wa padded
#define MB_AB     (MB_WAB   + MM*32)           // [2048][96] A bf16

__device__ inline u16 f2bf(float x) {
    union { float f; u32 u; } v; v.f = x;
    u32 r = v.u + 0x7fffu + ((v.u >> 16) & 1u);   // RNE
    return (u16)(r >> 16);
}
// pack 2 floats -> bf16x2 (round-half-up)
__device__ inline u32 pk2bf(float lo, float hi) {
    return ((__float_as_uint(lo) + 0x8000u) >> 16) |
           ((__float_as_uint(hi) + 0x8000u) & 0xffff0000u);
}
__device__ inline void unpack8(bf16x8 v, float* f) {
    const u32* d = (const u32*)&v;
    #pragma unroll
    for (int i = 0; i < 4; ++i) {
        f[2*i]   = __uint_as_float(d[i] << 16);
        f[2*i+1] = __uint_as_float(d[i] & 0xffff0000u);
    }
}
// async 16B global->LDS (lane slots must be wave-base + lane*16 -- they are)
__device__ inline void gl_lds16(const u16* g, u16* l) {
    __builtin_amdgcn_global_load_lds(
        (const __attribute__((address_space(1))) void*)g,
        (__attribute__((address_space(3))) void*)l, 16, 0, 0);
}
// swizzled bf16x8 fragment read: row-major [64 rows][64 u16], granule XOR row
__device__ inline bf16x8 frag64(const u16* X, int r, int g) {
    return *(const bf16x8*)&X[(r*8 + (g ^ (r & 7)))*8];
}

// ---------------------------------------------------------------------------
// weight prep: block 0 builds scorer Wm [96][96] + Wab [96][32];
// blocks 1..864 cast vw1, 865..1152 cast vw2
// ---------------------------------------------------------------------------
__global__ __launch_bounds__(256) void k_wprep(
    const float* __restrict__ sw1, const float* __restrict__ vw1,
    const float* __restrict__ vw2,
    u16* __restrict__ Wm, u16* __restrict__ Wab,
    u16* __restrict__ w1b, u16* __restrict__ w2b)
{
    int bx = blockIdx.x;
    if (bx == 0) {
        for (int i = threadIdx.x; i < MM*96; i += 256) {
            int m = i / 96, k = i % 96;
            float v = 0.f;
            if (k < 24)                 v = sw1[m*96 + 48 + k];         // Wc
            else if (k >= 32 && k < 56) v = sw1[m*96 + 72 + (k - 32)];  // Wd
            else if (k >= 64 && k < 88) v = sw1[m*96 + 24 + (k - 64)];  // Wb
            Wm[i] = f2bf(v);
        }
        for (int i = threadIdx.x; i < MM*32; i += 256) {
            int m = i >> 5, k = i & 31;
            Wab[i] = (k < 24) ? f2bf(sw1[m*96 + k]) : (u16)0;
        }
        return;
    }
    int idx = bx - 1;
    const float* src; u16* dst;
    if (idx < 864) { src = vw1; dst = w1b; }
    else           { idx -= 864; src = vw2; dst = w2b; }
    int i = (idx*256 + threadIdx.x) * 8;
    float4 a = *(const float4*)&src[i];
    float4 c = *(const float4*)&src[i+4];
    u16x4 lo = { f2bf(a.x), f2bf(a.y), f2bf(a.z), f2bf(a.w) };
    u16x4 hi = { f2bf(c.x), f2bf(c.y), f2bf(c.z), f2bf(c.w) };
    *(u16x4*)&dst[i]   = lo;
    *(u16x4*)&dst[i+4] = hi;
}

// ---------------------------------------------------------------------------
// K1: Z = H @ P^T via MFMA (64-row tiles, N=24 pad 32, K=768 BK=32,
// fp32->bf16 staging with prefetch).  Epilogue: write Z bf16; for the
// j-branch also A = Zj@Wa^T + sb1 via one more MFMA round (bf16).
// grid (32, 2): y==0 -> (Hj,pjw)->Zjp+Ab ; y==1 -> (Hi,piw)->Zip
// ---------------------------------------------------------------------------
__global__ __launch_bounds__(256) void k_zgemm(
    const float* __restrict__ Hj, const float* __restrict__ Hi,
    const float* __restrict__ pjw, const float* __restrict__ piw,
    const float* __restrict__ sw1, const float* __restrict__ sb1,
    const u16* __restrict__ Wab,
    u16* __restrict__ Zjp, u16* __restrict__ Zip, u16* __restrict__ Ab)
{
    int isJ = (blockIdx.y == 0);
    const float* H = isJ ? Hj : Hi;
    const float* P = isJ ? pjw : piw;
    u16* Zout = isJ ? Zjp : Zip;
    int n0 = blockIdx.x * 64;
    int tid = threadIdx.x, wave = tid >> 6, lane = tid & 63;
    int q = lane >> 4, l16 = lane & 15;
    __shared__ __align__(16) u16 As[64*32];
    __shared__ __align__(16) u16 Bs[32*32];
    __shared__ __align__(16) u16 zb[64*32];

    // zero B pad rows 24..31 (stay zero all loop)
    { int i = tid; Bs[(24 + (i >> 5))*32 + (i & 31)] = 0; }

    int arow = tid >> 2, aseg = tid & 3;
    const float* ah = H + (size_t)(n0 + arow)*HH + aseg*8;
    int brow = tid >> 2, bseg = tid & 3;               // valid for tid<96
    const float* bh = P + (size_t)brow*HH + bseg*8;
    int adst = arow*32 + ((aseg ^ (arow & 3))*8);
    int bdst = brow*32 + ((bseg ^ (brow & 3))*8);

    float4 xa = *(const float4*)(ah);
    float4 ya = *(const float4*)(ah + 4);
    float4 xb = {}, yb = {};
    if (tid < 96) { xb = *(const float4*)(bh); yb = *(const float4*)(bh + 4); }

    f32x4 acc0 = {}, acc1 = {};
    int ga = q ^ (l16 & 3);      // read granule swizzle (row = wave*16+l16; row&3 = l16&3)
    for (int k0 = 0; k0 < HH; k0 += 32) {
        { u32* w = (u32*)&As[adst];
          w[0] = pk2bf(xa.x, xa.y); w[1] = pk2bf(xa.z, xa.w);
          w[2] = pk2bf(ya.x, ya.y); w[3] = pk2bf(ya.z, ya.w); }
        if (tid < 96) {
          u32* w = (u32*)&Bs[bdst];
          w[0] = pk2bf(xb.x, xb.y); w[1] = pk2bf(xb.z, xb.w);
          w[2] = pk2bf(yb.x, yb.y); w[3] = pk2bf(yb.z, yb.w); }
        float4 nxa = {}, nya = {}, nxb = {}, nyb = {};
        if (k0 + 32 < HH) {
            nxa = *(const float4*)(ah + k0 + 32);
            nya = *(const float4*)(ah + k0 + 36);
            if (tid < 96) { nxb = *(const float4*)(bh + k0 + 32);
                            nyb = *(const float4*)(bh + k0 + 36); }
        }
        __syncthreads();
        bf16x8 af = *(const bf16x8*)&As[(wave*16 + l16)*32 + ga*8];
        bf16x8 b0 = *(const bf16x8*)&Bs[l16*32 + ga*8];
        bf16x8 b1 = *(const bf16x8*)&Bs[(16 + l16)*32 + ga*8];
        acc0 = __builtin_amdgcn_mfma_f32_16x16x32_bf16(af, b0, acc0, 0,0,0);
        acc1 = __builtin_amdgcn_mfma_f32_16x16x32_bf16(af, b1, acc1, 0,0,0);
        __syncthreads();
        xa = nxa; ya = nya; xb = nxb; yb = nyb;
    }
    // Z tile -> LDS bf16 (cols 24..31 are exact zeros from zeroed B rows)
    #pragma unroll
    for (int r = 0; r < 4; ++r) {
        zb[(wave*16 + q*4 + r)*32 + l16]      = f2bf(acc0[r]);
        zb[(wave*16 + q*4 + r)*32 + 16 + l16] = f2bf(acc1[r]);
    }
    __syncthreads();
    // write Z rows (8 u16 per thread, vectorized)
    { uint4 v = *(const uint4*)&zb[tid*8];
      *(uint4*)&Zout[(size_t)n0*32 + tid*8] = v; }
    if (isJ) {
        // A = Zj @ Wa^T + sb1, one MFMA round per n-tile
        bf16x8 af = *(const bf16x8*)&zb[(wave*16 + l16)*32 + q*8];
        #pragma unroll
        for (int nt = 0; nt < 6; ++nt) {
            bf16x8 bw = *(const bf16x8*)&Wab[(nt*16 + l16)*32 + q*8];
            f32x4 a = {};
            a = __builtin_amdgcn_mfma_f32_16x16x32_bf16(af, bw, a, 0,0,0);
            float bv = sb1[nt*16 + l16];
            #pragma unroll
            for (int r = 0; r < 4; ++r) {
                int bs = n0 + wave*16 + q*4 + r;
                Ab[(size_t)bs*MM + nt*16 + l16] = f2bf(a[r] + bv);
            }
        }
    }
}

// ---------------------------------------------------------------------------
// K2: register-fragment MFMA pairwise scorer + softmax (unchanged from R4,
// except A is now bf16).
// ---------------------------------------------------------------------------
__global__ __launch_bounds__(256) void k_pair_mfma(
    const u16* __restrict__ Zjp, const u16* __restrict__ Zip,
    const u16* __restrict__ Ab, const u16* __restrict__ Wm,
    const float* __restrict__ sw2, const float* __restrict__ mask,
    u16* __restrict__ probsb)
{
    int blk = blockIdx.x; int b = blk >> 8; int s0 = (blk & 255) * 2;
    int tid = threadIdx.x, wave = tid >> 6, lane = tid & 63;
    int q = lane >> 4, l16 = lane & 15;
    int si = wave & 1, half = wave >> 1;
    int s = s0 + si, bs = b*SS + s;
    __shared__ __align__(16) u16 ZiS[SS*32];      // 32 KB, chunk-swizzled
    __shared__ float logits[2][SS];               // 4 KB

    {
        const u16* zb = Zip + (size_t)b*SS*32;
        #pragma unroll
        for (int p = 0; p < 8; ++p) {
            int idx = p*256 + tid;
            int t = idx >> 2, c = idx & 3;
            int g = c ^ ((t + (t >> 2)) & 3);
            gl_lds16(zb + t*32 + g*8, ZiS + idx*8);
        }
    }

    bf16x8 zjf = *(const bf16x8*)&Zjp[(size_t)bs*32 + q*8];
    float zj[8]; unpack8(zjf, zj);
    bf16x8 afc[6], afd[6];
    #pragma unroll
    for (int mt = 0; mt < 6; ++mt) {
        const u16* wrow = &Wm[(mt*16 + l16)*96];
        bf16x8 wcf = *(const bf16x8*)&wrow[q*8];
        afd[mt]    = *(const bf16x8*)&wrow[32 + q*8];
        bf16x8 wbf = *(const bf16x8*)&wrow[64 + q*8];
        float fc[8], fb[8];
        unpack8(wcf, fc); unpack8(wbf, fb);
        u32 aval = (u32)Ab[(size_t)bs*MM + mt*16 + l16];
        union { u32 d[4]; bf16x8 v; } pk;
        #pragma unroll
        for (int i = 0; i < 4; ++i)
            pk.d[i] = pk2bf(fmaf(fc[2*i], zj[2*i], fb[2*i]),
                            fmaf(fc[2*i+1], zj[2*i+1], fb[2*i+1]));
        pk.d[0] = (q == 3) ? aval : pk.d[0];
        afc[mt] = pk.v;
    }
    float w2v[6][4];
    #pragma unroll
    for (int mt = 0; mt < 6; ++mt)
        #pragma unroll
        for (int r = 0; r < 4; ++r) w2v[mt][r] = sw2[mt*16 + q*4 + r];

    __syncthreads();

    for (int k = 0; k < 16; ++k) {
        int t0 = (half*16 + k) * 16;
        int trow = t0 + l16;
        int sw = q ^ ((trow + (trow >> 2)) & 3);
        bf16x8 zif = *(const bf16x8*)&ZiS[trow*32 + sw*8];
        float zi[8]; unpack8(zif, zi);
        union { u32 d[4]; bf16x8 v; } b1, b2;
        #pragma unroll
        for (int i = 0; i < 4; ++i)
            b1.d[i] = pk2bf(fabsf(zj[2*i] - zi[2*i]), fabsf(zj[2*i+1] - zi[2*i+1]));
        b2.v = zif;
        b2.d[0] = (q == 3) ? 0x3F80u : b2.d[0];
        f32x4 acc[6];
        #pragma unroll
        for (int mt = 0; mt < 6; ++mt) {
            f32x4 a = {};
            a = __builtin_amdgcn_mfma_f32_16x16x32_bf16(afc[mt], b2.v, a, 0,0,0);
            a = __builtin_amdgcn_mfma_f32_16x16x32_bf16(afd[mt], b1.v, a, 0,0,0);
            acc[mt] = a;
        }
        float p = 0.f;
        #pragma unroll
        for (int mt = 0; mt < 6; ++mt)
            #pragma unroll
            for (int r = 0; r < 4; ++r)
                p = fmaf(fmaxf(acc[mt][r], 0.f), w2v[mt][r], p);
        p += __shfl_xor(p, 16);
        p += __shfl_xor(p, 32);
        if (lane < 16) logits[si][t0 + lane] = p;
    }
    __syncthreads();

    if (wave < 2) {
        const float NEGF = -3.4028234663852886e38f;
        int bss = b*SS + s0 + wave;
        float l[8], e[8];
        float mx = -INFINITY;
        #pragma unroll
        for (int i = 0; i < 8; ++i) {
            int idx = lane + i*64;
            l[i] = logits[wave][idx] + (1.f - mask[b*SS + idx]) * NEGF;
            mx = fmaxf(mx, l[i]);
        }
        #pragma unroll
        for (int off = 32; off > 0; off >>= 1) mx = fmaxf(mx, __shfl_xor(mx, off));
        float sum = 0.f;
        #pragma unroll
        for (int i = 0; i < 8; ++i) { e[i] = __expf(l[i] - mx); sum += e[i]; }
        #pragma unroll
        for (int off = 32; off > 0; off >>= 1) sum += __shfl_xor(sum, off);
        float inv = 1.f / sum;
        #pragma unroll
        for (int i = 0; i < 8; ++i)
            probsb[(size_t)bss*SS + lane + i*64] = f2bf(e[i] * inv);
    }
}

// ---------------------------------------------------------------------------
// transpose Hi -> HiT bf16 [b][h][t], 64x64 tiles, vectorized 16B stores
// ---------------------------------------------------------------------------
__global__ __launch_bounds__(256) void k_hit(
    const float* __restrict__ Hi, u16* __restrict__ HiTb)
{
    int b = blockIdx.z, t0 = blockIdx.x*64, h0 = blockIdx.y*64;
    __shared__ u16 tile[64*74];
    int r = threadIdx.x >> 2, cs = threadIdx.x & 3;
    const float* src = Hi + ((size_t)(b*SS) + t0 + r)*HH + h0 + cs*16;
    u16* dst = &tile[r*74 + cs*16];
    #pragma unroll
    for (int i = 0; i < 4; ++i) {
        float4 v = *(const float4*)(src + i*4);
        *(u32*)&dst[i*4]     = pk2bf(v.x, v.y);
        *(u32*)&dst[i*4 + 2] = pk2bf(v.z, v.w);
    }
    __syncthreads();
    int hr = threadIdx.x >> 2;
    u16 outv[16];
    #pragma unroll
    for (int i = 0; i < 16; ++i) outv[i] = tile[(cs*16 + i)*74 + hr];
    u16* o = HiTb + ((size_t)b*HH + h0 + hr)*SS + t0 + cs*16;
    *(uint4*)o       = *(const uint4*)&outv[0];
    *(uint4*)(o + 8) = *(const uint4*)&outv[8];
}

// ---------------------------------------------------------------------------
// K3: ctx via MFMA, 64x64 tile, BK=64, row-XOR granule swizzle,
// fused msg_in epilogue.
// ---------------------------------------------------------------------------
__global__ __launch_bounds__(256) void k_ctx_mfma(
    const u16* __restrict__ probsb, const u16* __restrict__ HiTb,
    const float* __restrict__ Hj, u16* __restrict__ msginb)
{
    int b = blockIdx.z;
    int h0 = blockIdx.x * 64;
    int s0 = blockIdx.y * 64;
    int tid = threadIdx.x;
    __shared__ __align__(16) u16 As[64*64];
    __shared__ __align__(16) u16 Bs[64*64];
    int wave = tid >> 6, lane = tid & 63;
    int wr = (wave >> 1) * 32, wc = (wave & 1) * 32;
    int q = lane >> 4, l16 = lane & 15;
    f32x4 acc[2][2] = {};
    const u16* ag = probsb + ((size_t)(b*SS) + s0)*SS;
    const u16* bg = HiTb + ((size_t)b*HH + h0)*SS;
    for (int k0 = 0; k0 < SS; k0 += 64) {
        #pragma unroll
        for (int p = 0; p < 2; ++p) {
            int sl = p*256 + tid; int rr = sl >> 3, gi = sl & 7, g = gi ^ (rr & 7);
            gl_lds16(ag + (size_t)rr*SS + k0 + g*8, As + sl*8);
            gl_lds16(bg + (size_t)rr*SS + k0 + g*8, Bs + sl*8);
        }
        __syncthreads();
        #pragma unroll
        for (int ks = 0; ks < 2; ++ks) {
            int g = ks*4 + q;
            bf16x8 a0 = frag64(As, wr + l16, g);
            bf16x8 a1 = frag64(As, wr + 16 + l16, g);
            bf16x8 b0 = frag64(Bs, wc + l16, g);
            bf16x8 b1 = frag64(Bs, wc + 16 + l16, g);
            acc[0][0] = __builtin_amdgcn_mfma_f32_16x16x32_bf16(a0, b0, acc[0][0], 0,0,0);
            acc[0][1] = __builtin_amdgcn_mfma_f32_16x16x32_bf16(a0, b1, acc[0][1], 0,0,0);
            acc[1][0] = __builtin_amdgcn_mfma_f32_16x16x32_bf16(a1, b0, acc[1][0], 0,0,0);
            acc[1][1] = __builtin_amdgcn_mfma_f32_16x16x32_bf16(a1, b1, acc[1][1], 0,0,0);
        }
        __syncthreads();
    }
    #pragma unroll
    for (int rt = 0; rt < 2; ++rt) {
        #pragma unroll
        for (int ct = 0; ct < 2; ++ct) {
            int h = h0 + wc + ct*16 + l16;
            #pragma unroll
            for (int r = 0; r < 4; ++r) {
                int s = s0 + wr + rt*16 + q*4 + r;
                float v = acc[rt][ct][r];
                float hj = Hj[((size_t)(b*SS) + s)*HH + h];
                u16* mb = msginb + (size_t)(b*SS + s)*K3H + h;
                mb[0]    = f2bf(v);
                mb[HH]   = f2bf(hj);
                mb[2*HH] = f2bf(v * hj);
            }
        }
    }
}

// ---------------------------------------------------------------------------
// G1: h1 = relu(msgin @ w1^T + vb1) -> bf16.  64x64 tile, BK=64.
// ---------------------------------------------------------------------------
__global__ __launch_bounds__(256) void k_mfma_gemm1(
    const u16* __restrict__ Abf, const u16* __restrict__ Bbf,
    const float* __restrict__ bias, u16* __restrict__ Cbf)
{
    int o0 = blockIdx.x * 64;
    int n0 = blockIdx.y * 64;
    int tid = threadIdx.x;
    __shared__ __align__(16) u16 As[64*64];
    __shared__ __align__(16) u16 Bs[64*64];
    int wave = tid >> 6, lane = tid & 63;
    int wr = (wave >> 1) * 32, wc = (wave & 1) * 32;
    int q = lane >> 4, l16 = lane & 15;
    f32x4 acc[2][2] = {};
    const u16* ag = Abf + (size_t)n0*K3H;
    const u16* bg = Bbf + (size_t)o0*K3H;
    for (int k0 = 0; k0 < K3H; k0 += 64) {
        #pragma unroll
        for (int p = 0; p < 2; ++p) {
            int sl = p*256 + tid; int rr = sl >> 3, gi = sl & 7, g = gi ^ (rr & 7);
            gl_lds16(ag + (size_t)rr*K3H + k0 + g*8, As + sl*8);
            gl_lds16(bg + (size_t)rr*K3H + k0 + g*8, Bs + sl*8);
        }
        __syncthreads();
        #pragma unroll
        for (int ks = 0; ks < 2; ++ks) {
            int g = ks*4 + q;
            bf16x8 a0 = frag64(As, wr + l16, g);
            bf16x8 a1 = frag64(As, wr + 16 + l16, g);
            bf16x8 b0 = frag64(Bs, wc + l16, g);
            bf16x8 b1 = frag64(Bs, wc + 16 + l16, g);
            acc[0][0] = __builtin_amdgcn_mfma_f32_16x16x32_bf16(a0, b0, acc[0][0], 0,0,0);
            acc[0][1] = __builtin_amdgcn_mfma_f32_16x16x32_bf16(a0, b1, acc[0][1], 0,0,0);
            acc[1][0] = __builtin_amdgcn_mfma_f32_16x16x32_bf16(a1, b0, acc[1][0], 0,0,0);
            acc[1][1] = __builtin_amdgcn_mfma_f32_16x16x32_bf16(a1, b1, acc[1][1], 0,0,0);
        }
        __syncthreads();
    }
    #pragma unroll
    for (int rt = 0; rt < 2; ++rt) {
        #pragma unroll
        for (int ct = 0; ct < 2; ++ct) {
            int o = o0 + wc + ct*16 + l16;
            float bv = bias[o];
            #pragma unroll
            for (int r = 0; r < 4; ++r) {
                int m = n0 + wr + rt*16 + q*4 + r;
                Cbf[(size_t)m*OH + o] = f2bf(fmaxf(acc[rt][ct][r] + bv, 0.f));
            }
        }
    }
}

// ---------------------------------------------------------------------------
// G2: out = alpha * (h1 @ w2^T + vb2).  64x64 tile, BK=64.
// ---------------------------------------------------------------------------
__global__ __launch_bounds__(256) void k_mfma_gemm2(
    const u16* __restrict__ Abf, const u16* __restrict__ Bbf,
    const float* __restrict__ bias, const float* __restrict__ alpha,
    float* __restrict__ out)
{
    int o0 = blockIdx.x * 64;
    int n0 = blockIdx.y * 64;
    int tid = threadIdx.x;
    __shared__ __align__(16) u16 As[64*64];
    __shared__ __align__(16) u16 Bs[64*64];
    int wave = tid >> 6, lane = tid & 63;
    int wr = (wave >> 1) * 32, wc = (wave & 1) * 32;
    int q = lane >> 4, l16 = lane & 15;
    f32x4 acc[2][2] = {};
    const u16* ag = Abf + (size_t)n0*OH;
    const u16* bg = Bbf + (size_t)o0*OH;
    for (int k0 = 0; k0 < OH; k0 += 64) {
        #pragma unroll
        for (int p = 0; p < 2; ++p) {
            int sl = p*256 + tid; int rr = sl >> 3, gi = sl & 7, g = gi ^ (rr & 7);
            gl_lds16(ag + (size_t)rr*OH + k0 + g*8, As + sl*8);
            gl_lds16(bg + (size_t)rr*OH + k0 + g*8, Bs + sl*8);
        }
        __syncthreads();
        #pragma unroll
        for (int ks = 0; ks < 2; ++ks) {
            int g = ks*4 + q;
            bf16x8 a0 = frag64(As, wr + l16, g);
            bf16x8 a1 = frag64(As, wr + 16 + l16, g);
            bf16x8 b0 = frag64(Bs, wc + l16, g);
            bf16x8 b1 = frag64(Bs, wc + 16 + l16, g);
            acc[0][0] = __builtin_amdgcn_mfma_f32_16x16x32_bf16(a0, b0, acc[0][0], 0,0,0);
            acc[0][1] = __builtin_amdgcn_mfma_f32_16x16x32_bf16(a0, b1, acc[0][1], 0,0,0);
            acc[1][0] = __builtin_amdgcn_mfma_f32_16x16x32_bf16(a1, b0, acc[1][0], 0,0,0);
            acc[1][1] = __builtin_amdgcn_mfma_f32_16x16x32_bf16(a1, b1, acc[1][1], 0,0,0);
        }
        __syncthreads();
    }
    float al = alpha[0];
    #pragma unroll
    for (int rt = 0; rt < 2; ++rt) {
        #pragma unroll
        for (int ct = 0; ct < 2; ++ct) {
            int o = o0 + wc + ct*16 + l16;
            float bv = bias[o];
            #pragma unroll
            for (int r = 0; r < 4; ++r) {
                int m = n0 + wr + rt*16 + q*4 + r;
                out[(size_t)m*HH + o] = al * (acc[rt][ct][r] + bv);
            }
        }
    }
}

// ---------------------------------------------------------------------------
extern "C" void kernel_launch(void* const* d_in, const int* in_sizes, int n_in,
                              void* d_out, int out_size, void* d_ws, size_t ws_size,
                              hipStream_t stream) {
    const float* Hj    = (const float*)d_in[0];
    const float* Hi    = (const float*)d_in[1];
    const float* amask = (const float*)d_in[2];
    const float* pjw   = (const float*)d_in[3];
    const float* piw   = (const float*)d_in[4];
    const float* sw1   = (const float*)d_in[5];
    const float* sb1   = (const float*)d_in[6];
    const float* sw2   = (const float*)d_in[7];
    const float* sb2   = (const float*)d_in[8];
    const float* vw1   = (const float*)d_in[9];
    const float* vb1   = (const float*)d_in[10];
    const float* vw2   = (const float*)d_in[11];
    const float* vb2   = (const float*)d_in[12];
    const float* alpha = (const float*)d_in[13];
    float* out = (float*)d_out;
    (void)sb2; // softmax is shift-invariant; sb2 cancels

    u16* bfbase = (u16*)d_ws;
    u16* msginb = bfbase + MB_MSGIN;
    u16* h1b    = bfbase + MB_H1;
    u16* w1b    = bfbase + MB_W1;
    u16* w2b    = bfbase + MB_W2;
    u16* probsb = bfbase + MB_PROBS;
    u16* hitb   = bfbase + MB_HIT;
    u16* zjp    = bfbase + MB_ZJP;
    u16* zip    = bfbase + MB_ZIP;
    u16* wm     = bfbase + MB_WM;
    u16* wab    = bfbase + MB_WAB;
    u16* ab     = bfbase + MB_AB;

    k_wprep<<<1 + 864 + 288, 256, 0, stream>>>(sw1, vw1, vw2, wm, wab, w1b, w2b);
    k_zgemm<<<dim3(32, 2), 256, 0, stream>>>(Hj, Hi, pjw, piw, sw1, sb1, wab, zjp, zip, ab);
    k_hit<<<dim3(SS/64, HH/64, BB), 256, 0, stream>>>(Hi, hitb);
    k_pair_mfma<<<BB*SS/2, 256, 0, stream>>>(zjp, zip, ab, wm, sw2, amask, probsb);
    k_ctx_mfma<<<dim3(HH/64, SS/64, BB), 256, 0, stream>>>(probsb, hitb, Hj, msginb);
    k_mfma_gemm1<<<dim3(OH/64, BB*SS/64), 256, 0, stream>>>(msginb, w1b, vb1, h1b);
    k_mfma_gemm2<<<dim3(HH/64, BB*SS/64), 256, 0, stream>>>(h1b, w2b, vb2, alpha, out);
}

// Round 7
// 191.021 us; speedup vs baseline: 2.7133x; 1.0180x over previous
//
#include <hip/hip_runtime.h>
#include <hip/hip_bf16.h>
#include <math.h>

#define BB 4
#define SS 512
#define HH 768
#define DD 24
#define MM 96
#define OH 768      // OUT_HID
#define K3H 2304    // 3*H

typedef unsigned short u16;
typedef unsigned int u32;
typedef short bf16x8 __attribute__((ext_vector_type(8)));
typedef float f32x4 __attribute__((ext_vector_type(4)));
typedef u16 u16x4 __attribute__((ext_vector_type(4)));

// bf16 workspace (offsets in u16 from ws base)
#define MB_MSGIN  0                            // [2048][2304]
#define MB_H1     (MB_MSGIN + BB*SS*K3H)       // [2048][768]
#define MB_W1     (MB_H1    + BB*SS*OH)        // [768][2304]
#define MB_W2     (MB_W1    + OH*K3H)          // [768][768]
#define MB_PROBS  (MB_W2    + OH*HH)           // [2048][512]
#define MB_HIT    (MB_PROBS + BB*SS*SS)        // [b][768][512]
#define MB_ZJP    (MB_HIT   + BB*HH*SS)        // [2048][32] bf16, cols>=24 zero
#define MB_ZIP    (MB_ZJP   + BB*SS*32)        // [2048][32]
#define MB_WM     (MB_ZIP   + BB*SS*32)        // [96][96] scorer W
#define MB_WAB    (MB_WM    + MM*96)           // [96][32]  Wa padded
#define MB_AB     (MB_WAB   + MM*32)           // [2048][96] A bf16

__device__ inline u16 f2bf(float x) {
    union { float f; u32 u; } v; v.f = x;
    u32 r = v.u + 0x7fffu + ((v.u >> 16) & 1u);   // RNE
    return (u16)(r >> 16);
}
__device__ inline u32 pk2bf(float lo, float hi) {
    return ((__float_as_uint(lo) + 0x8000u) >> 16) |
           ((__float_as_uint(hi) + 0x8000u) & 0xffff0000u);
}
__device__ inline void unpack8(bf16x8 v, float* f) {
    const u32* d = (const u32*)&v;
    #pragma unroll
    for (int i = 0; i < 4; ++i) {
        f[2*i]   = __uint_as_float(d[i] << 16);
        f[2*i+1] = __uint_as_float(d[i] & 0xffff0000u);
    }
}
__device__ inline void gl_lds16(const u16* g, u16* l) {
    __builtin_amdgcn_global_load_lds(
        (const __attribute__((address_space(1))) void*)g,
        (__attribute__((address_space(3))) void*)l, 16, 0, 0);
}
__device__ inline bf16x8 frag64(const u16* X, int r, int g) {
    return *(const bf16x8*)&X[(r*8 + (g ^ (r & 7)))*8];
}

// ---------------------------------------------------------------------------
// W0: tiny scorer-weight builder (must precede prep's zgemm epilogue)
// ---------------------------------------------------------------------------
__global__ __launch_bounds__(256) void k_wm(
    const float* __restrict__ sw1, u16* __restrict__ Wm, u16* __restrict__ Wab)
{
    for (int i = threadIdx.x; i < MM*96; i += 256) {
        int m = i / 96, k = i % 96;
        float v = 0.f;
        if (k < 24)                 v = sw1[m*96 + 48 + k];         // Wc
        else if (k >= 32 && k < 56) v = sw1[m*96 + 72 + (k - 32)];  // Wd
        else if (k >= 64 && k < 88) v = sw1[m*96 + 24 + (k - 64)];  // Wb
        Wm[i] = f2bf(v);
    }
    for (int i = threadIdx.x; i < MM*32; i += 256) {
        int m = i >> 5, k = i & 31;
        Wab[i] = (k < 24) ? f2bf(sw1[m*96 + k]) : (u16)0;
    }
}

// ---------------------------------------------------------------------------
// PREP (one launch, 2304 blocks):
//  [0,64)      : Z = H@P^T MFMA (j/i) + A epilogue
//  [64,928)    : cast vw1 -> w1b
//  [928,1216)  : cast vw2 -> w2b
//  [1216,1920) : cast Hj  -> msgin middle third   (768 blocks)
//  [1920,2304) : transpose Hi -> HiT bf16 [b][h][t]
// ---------------------------------------------------------------------------
#define PZ_END   64
#define PC1_END  928
#define PC2_END  1216
#define PHJ_END  1984
#define PHT_END  2368

__global__ __launch_bounds__(256) void k_prep(
    const float* __restrict__ Hj, const float* __restrict__ Hi,
    const float* __restrict__ pjw, const float* __restrict__ piw,
    const float* __restrict__ sb1,
    const float* __restrict__ vw1, const float* __restrict__ vw2,
    const u16* __restrict__ Wab,
    u16* __restrict__ w1b, u16* __restrict__ w2b,
    u16* __restrict__ Zjp, u16* __restrict__ Zip, u16* __restrict__ Ab,
    u16* __restrict__ msginb, u16* __restrict__ HiTb)
{
    __shared__ __align__(16) u16 smem[5120];
    int bx = blockIdx.x;
    int tid = threadIdx.x;

    if (bx < PZ_END) {
        int idx = bx;
        int isJ = (idx < 32);
        int n0 = (idx & 31) * 64;
        const float* H = isJ ? Hj : Hi;
        const float* P = isJ ? pjw : piw;
        u16* Zout = isJ ? Zjp : Zip;
        u16* As = smem;
        u16* Bs = smem + 2048;
        u16* zb = smem + 3072;
        int wave = tid >> 6, lane = tid & 63;
        int q = lane >> 4, l16 = lane & 15;

        { int i = tid; Bs[(24 + (i >> 5))*32 + (i & 31)] = 0; }

        int arow = tid >> 2, aseg = tid & 3;
        const float* ah = H + (size_t)(n0 + arow)*HH + aseg*8;
        const float* bh = P + (size_t)arow*HH + aseg*8;
        int adst = arow*32 + ((aseg ^ (arow & 3))*8);

        float4 xa = *(const float4*)(ah);
        float4 ya = *(const float4*)(ah + 4);
        float4 xb = {}, yb = {};
        if (tid < 96) { xb = *(const float4*)(bh); yb = *(const float4*)(bh + 4); }

        f32x4 acc0 = {}, acc1 = {};
        int ga = q ^ (l16 & 3);
        for (int k0 = 0; k0 < HH; k0 += 32) {
            { u32* w = (u32*)&As[adst];
              w[0] = pk2bf(xa.x, xa.y); w[1] = pk2bf(xa.z, xa.w);
              w[2] = pk2bf(ya.x, ya.y); w[3] = pk2bf(ya.z, ya.w); }
            if (tid < 96) {
              u32* w = (u32*)&Bs[adst];
              w[0] = pk2bf(xb.x, xb.y); w[1] = pk2bf(xb.z, xb.w);
              w[2] = pk2bf(yb.x, yb.y); w[3] = pk2bf(yb.z, yb.w); }
            float4 nxa = {}, nya = {}, nxb = {}, nyb = {};
            if (k0 + 32 < HH) {
                nxa = *(const float4*)(ah + k0 + 32);
                nya = *(const float4*)(ah + k0 + 36);
                if (tid < 96) { nxb = *(const float4*)(bh + k0 + 32);
                                nyb = *(const float4*)(bh + k0 + 36); }
            }
            __syncthreads();
            bf16x8 af = *(const bf16x8*)&As[(wave*16 + l16)*32 + ga*8];
            bf16x8 b0 = *(const bf16x8*)&Bs[l16*32 + ga*8];
            bf16x8 b1 = *(const bf16x8*)&Bs[(16 + l16)*32 + ga*8];
            acc0 = __builtin_amdgcn_mfma_f32_16x16x32_bf16(af, b0, acc0, 0,0,0);
            acc1 = __builtin_amdgcn_mfma_f32_16x16x32_bf16(af, b1, acc1, 0,0,0);
            __syncthreads();
            xa = nxa; ya = nya; xb = nxb; yb = nyb;
        }
        #pragma unroll
        for (int r = 0; r < 4; ++r) {
            zb[(wave*16 + q*4 + r)*32 + l16]      = f2bf(acc0[r]);
            zb[(wave*16 + q*4 + r)*32 + 16 + l16] = f2bf(acc1[r]);
        }
        __syncthreads();
        { uint4 v = *(const uint4*)&zb[tid*8];
          *(uint4*)&Zout[(size_t)n0*32 + tid*8] = v; }
        if (isJ) {
            bf16x8 af = *(const bf16x8*)&zb[(wave*16 + l16)*32 + q*8];
            #pragma unroll
            for (int nt = 0; nt < 6; ++nt) {
                bf16x8 bw = *(const bf16x8*)&Wab[(nt*16 + l16)*32 + q*8];
                f32x4 a = {};
                a = __builtin_amdgcn_mfma_f32_16x16x32_bf16(af, bw, a, 0,0,0);
                float bv = sb1[nt*16 + l16];
                #pragma unroll
                for (int r = 0; r < 4; ++r) {
                    int bs = n0 + wave*16 + q*4 + r;
                    Ab[(size_t)bs*MM + nt*16 + l16] = f2bf(a[r] + bv);
                }
            }
        }
    } else if (bx < PC2_END) {
        int idx; const float* src; u16* dst;
        if (bx < PC1_END) { idx = bx - PZ_END;  src = vw1; dst = w1b; }
        else              { idx = bx - PC1_END; src = vw2; dst = w2b; }
        int i = (idx*256 + tid) * 8;
        float4 a = *(const float4*)&src[i];
        float4 c = *(const float4*)&src[i+4];
        u16x4 lo = { f2bf(a.x), f2bf(a.y), f2bf(a.z), f2bf(a.w) };
        u16x4 hi = { f2bf(c.x), f2bf(c.y), f2bf(c.z), f2bf(c.w) };
        *(u16x4*)&dst[i]   = lo;
        *(u16x4*)&dst[i+4] = hi;
    } else if (bx < PHJ_END) {
        int idx = bx - PC2_END;
        int e = (idx*256 + tid) * 8;               // linear over 2048*768
        int n = e / HH, k = e - n*HH;
        float4 a = *(const float4*)&Hj[e];
        float4 c = *(const float4*)&Hj[e+4];
        u16* dst = msginb + (size_t)n*K3H + HH + k;
        u16x4 lo = { f2bf(a.x), f2bf(a.y), f2bf(a.z), f2bf(a.w) };
        u16x4 hi = { f2bf(c.x), f2bf(c.y), f2bf(c.z), f2bf(c.w) };
        *(u16x4*)&dst[0] = lo;
        *(u16x4*)&dst[4] = hi;
    } else {
        int idx = bx - PHJ_END;
        int t0 = (idx & 7) * 64;
        int h0 = ((idx >> 3) % 12) * 64;
        int b  = idx / 96;
        u16* tile = smem;                          // 64*74 = 4736 u16
        int r = tid >> 2, cs = tid & 3;
        const float* src = Hi + ((size_t)(b*SS) + t0 + r)*HH + h0 + cs*16;
        u16* dst = &tile[r*74 + cs*16];
        #pragma unroll
        for (int i = 0; i < 4; ++i) {
            float4 v = *(const float4*)(src + i*4);
            *(u32*)&dst[i*4]     = pk2bf(v.x, v.y);
            *(u32*)&dst[i*4 + 2] = pk2bf(v.z, v.w);
        }
        __syncthreads();
        int hr = tid >> 2;
        u16 outv[16];
        #pragma unroll
        for (int i = 0; i < 16; ++i) outv[i] = tile[(cs*16 + i)*74 + hr];
        u16* o = HiTb + ((size_t)b*HH + h0 + hr)*SS + t0 + cs*16;
        *(uint4*)o       = *(const uint4*)&outv[0];
        *(uint4*)(o + 8) = *(const uint4*)&outv[8];
    }
}

// ---------------------------------------------------------------------------
// K2: register-fragment MFMA pairwise scorer + softmax.
// ---------------------------------------------------------------------------
__global__ __launch_bounds__(256) void k_pair_mfma(
    const u16* __restrict__ Zjp, const u16* __restrict__ Zip,
    const u16* __restrict__ Ab, const u16* __restrict__ Wm,
    const float* __restrict__ sw2, const float* __restrict__ mask,
    u16* __restrict__ probsb)
{
    int blk = blockIdx.x; int b = blk >> 8; int s0 = (blk & 255) * 2;
    int tid = threadIdx.x, wave = tid >> 6, lane = tid & 63;
    int q = lane >> 4, l16 = lane & 15;
    int si = wave & 1, half = wave >> 1;
    int s = s0 + si, bs = b*SS + s;
    __shared__ __align__(16) u16 ZiS[SS*32];
    __shared__ float logits[2][SS];

    {
        const u16* zb = Zip + (size_t)b*SS*32;
        #pragma unroll
        for (int p = 0; p < 8; ++p) {
            int idx = p*256 + tid;
            int t = idx >> 2, c = idx & 3;
            int g = c ^ ((t + (t >> 2)) & 3);
            gl_lds16(zb + t*32 + g*8, ZiS + idx*8);
        }
    }

    bf16x8 zjf = *(const bf16x8*)&Zjp[(size_t)bs*32 + q*8];
    float zj[8]; unpack8(zjf, zj);
    bf16x8 afc[6], afd[6];
    #pragma unroll
    for (int mt = 0; mt < 6; ++mt) {
        const u16* wrow = &Wm[(mt*16 + l16)*96];
        bf16x8 wcf = *(const bf16x8*)&wrow[q*8];
        afd[mt]    = *(const bf16x8*)&wrow[32 + q*8];
        bf16x8 wbf = *(const bf16x8*)&wrow[64 + q*8];
        float fc[8], fb[8];
        unpack8(wcf, fc); unpack8(wbf, fb);
        u32 aval = (u32)Ab[(size_t)bs*MM + mt*16 + l16];
        union { u32 d[4]; bf16x8 v; } pk;
        #pragma unroll
        for (int i = 0; i < 4; ++i)
            pk.d[i] = pk2bf(fmaf(fc[2*i], zj[2*i], fb[2*i]),
                            fmaf(fc[2*i+1], zj[2*i+1], fb[2*i+1]));
        pk.d[0] = (q == 3) ? aval : pk.d[0];
        afc[mt] = pk.v;
    }
    float w2v[6][4];
    #pragma unroll
    for (int mt = 0; mt < 6; ++mt)
        #pragma unroll
        for (int r = 0; r < 4; ++r) w2v[mt][r] = sw2[mt*16 + q*4 + r];

    __syncthreads();

    for (int k = 0; k < 16; ++k) {
        int t0 = (half*16 + k) * 16;
        int trow = t0 + l16;
        int sw = q ^ ((trow + (trow >> 2)) & 3);
        bf16x8 zif = *(const bf16x8*)&ZiS[trow*32 + sw*8];
        float zi[8]; unpack8(zif, zi);
        union { u32 d[4]; bf16x8 v; } b1, b2;
        #pragma unroll
        for (int i = 0; i < 4; ++i)
            b1.d[i] = pk2bf(fabsf(zj[2*i] - zi[2*i]), fabsf(zj[2*i+1] - zi[2*i+1]));
        b2.v = zif;
        b2.d[0] = (q == 3) ? 0x3F80u : b2.d[0];
        f32x4 acc[6];
        #pragma unroll
        for (int mt = 0; mt < 6; ++mt) {
            f32x4 a = {};
            a = __builtin_amdgcn_mfma_f32_16x16x32_bf16(afc[mt], b2.v, a, 0,0,0);
            a = __builtin_amdgcn_mfma_f32_16x16x32_bf16(afd[mt], b1.v, a, 0,0,0);
            acc[mt] = a;
        }
        float p = 0.f;
        #pragma unroll
        for (int mt = 0; mt < 6; ++mt)
            #pragma unroll
            for (int r = 0; r < 4; ++r)
                p = fmaf(fmaxf(acc[mt][r], 0.f), w2v[mt][r], p);
        p += __shfl_xor(p, 16);
        p += __shfl_xor(p, 32);
        if (lane < 16) logits[si][t0 + lane] = p;
    }
    __syncthreads();

    if (wave < 2) {
        const float NEGF = -3.4028234663852886e38f;
        int bss = b*SS + s0 + wave;
        float l[8], e[8];
        float mx = -INFINITY;
        #pragma unroll
        for (int i = 0; i < 8; ++i) {
            int idx = lane + i*64;
            l[i] = logits[wave][idx] + (1.f - mask[b*SS + idx]) * NEGF;
            mx = fmaxf(mx, l[i]);
        }
        #pragma unroll
        for (int off = 32; off > 0; off >>= 1) mx = fmaxf(mx, __shfl_xor(mx, off));
        float sum = 0.f;
        #pragma unroll
        for (int i = 0; i < 8; ++i) { e[i] = __expf(l[i] - mx); sum += e[i]; }
        #pragma unroll
        for (int off = 32; off > 0; off >>= 1) sum += __shfl_xor(sum, off);
        float inv = 1.f / sum;
        #pragma unroll
        for (int i = 0; i < 8; ++i)
            probsb[(size_t)bss*SS + lane + i*64] = f2bf(e[i] * inv);
    }
}

// ---------------------------------------------------------------------------
// K3: ctx via MFMA, 64x64 tile, BK=64.  Epilogue: LDS remap -> coalesced
// uint4 stores of ctx and ctx*Hj (Hj read back bf16 from msgin mid third).
// ---------------------------------------------------------------------------
__global__ __launch_bounds__(256) void k_ctx_mfma(
    const u16* __restrict__ probsb, const u16* __restrict__ HiTb,
    u16* __restrict__ msginb)
{
    int b = blockIdx.z;
    int h0 = blockIdx.x * 64;
    int s0 = blockIdx.y * 64;
    int tid = threadIdx.x;
    __shared__ __align__(16) u16 smem[8192];      // As | Bs, reused as zb
    u16* As = smem;
    u16* Bs = smem + 4096;
    int wave = tid >> 6, lane = tid & 63;
    int wr = (wave >> 1) * 32, wc = (wave & 1) * 32;
    int q = lane >> 4, l16 = lane & 15;
    f32x4 acc[2][2] = {};
    const u16* ag = probsb + ((size_t)(b*SS) + s0)*SS;
    const u16* bg = HiTb + ((size_t)b*HH + h0)*SS;
    for (int k0 = 0; k0 < SS; k0 += 64) {
        #pragma unroll
        for (int p = 0; p < 2; ++p) {
            int sl = p*256 + tid; int rr = sl >> 3, gi = sl & 7, g = gi ^ (rr & 7);
            gl_lds16(ag + (size_t)rr*SS + k0 + g*8, As + sl*8);
            gl_lds16(bg + (size_t)rr*SS + k0 + g*8, Bs + sl*8);
        }
        __syncthreads();
        #pragma unroll
        for (int ks = 0; ks < 2; ++ks) {
            int g = ks*4 + q;
            bf16x8 a0 = frag64(As, wr + l16, g);
            bf16x8 a1 = frag64(As, wr + 16 + l16, g);
            bf16x8 b0 = frag64(Bs, wc + l16, g);
            bf16x8 b1 = frag64(Bs, wc + 16 + l16, g);
            acc[0][0] = __builtin_amdgcn_mfma_f32_16x16x32_bf16(a0, b0, acc[0][0], 0,0,0);
            acc[0][1] = __builtin_amdgcn_mfma_f32_16x16x32_bf16(a0, b1, acc[0][1], 0,0,0);
            acc[1][0] = __builtin_amdgcn_mfma_f32_16x16x32_bf16(a1, b0, acc[1][0], 0,0,0);
            acc[1][1] = __builtin_amdgcn_mfma_f32_16x16x32_bf16(a1, b1, acc[1][1], 0,0,0);
        }
        __syncthreads();
    }
    u16* zb = smem;   // stride 72 u16 (16B-aligned rows)
    #pragma unroll
    for (int rt = 0; rt < 2; ++rt)
        #pragma unroll
        for (int ct = 0; ct < 2; ++ct) {
            int hl = wc + ct*16 + l16;
            #pragma unroll
            for (int r = 0; r < 4; ++r)
                zb[(wr + rt*16 + q*4 + r)*72 + hl] = f2bf(acc[rt][ct][r]);
        }
    __syncthreads();
    {
        int s_l = tid >> 2, seg = tid & 3;
        u16 cv[16], hv[16], pv[16];
        *(uint4*)&cv[0] = *(const uint4*)&zb[s_l*72 + seg*16];
        *(uint4*)&cv[8] = *(const uint4*)&zb[s_l*72 + seg*16 + 8];
        u16* row = msginb + (size_t)(b*SS + s0 + s_l)*K3H;
        int hc = h0 + seg*16;
        *(uint4*)&hv[0] = *(const uint4*)&row[HH + hc];
        *(uint4*)&hv[8] = *(const uint4*)&row[HH + hc + 8];
        #pragma unroll
        for (int i = 0; i < 8; ++i) {
            float c0 = __uint_as_float((u32)cv[2*i] << 16);
            float c1 = __uint_as_float((u32)cv[2*i+1] << 16);
            float g0 = __uint_as_float((u32)hv[2*i] << 16);
            float g1 = __uint_as_float((u32)hv[2*i+1] << 16);
            u32 pr = pk2bf(c0*g0, c1*g1);
            pv[2*i] = (u16)pr; pv[2*i+1] = (u16)(pr >> 16);
        }
        *(uint4*)&row[hc]     = *(const uint4*)&cv[0];
        *(uint4*)&row[hc + 8] = *(const uint4*)&cv[8];
        *(uint4*)&row[2*HH + hc]     = *(const uint4*)&pv[0];
        *(uint4*)&row[2*HH + hc + 8] = *(const uint4*)&pv[8];
    }
}

// ---------------------------------------------------------------------------
// G1: h1 = relu(msgin @ w1^T + vb1) -> bf16.  64x64 tile, BK=64.
// ---------------------------------------------------------------------------
__global__ __launch_bounds__(256) void k_mfma_gemm1(
    const u16* __restrict__ Abf, const u16* __restrict__ Bbf,
    const float* __restrict__ bias, u16* __restrict__ Cbf)
{
    int o0 = blockIdx.x * 64;
    int n0 = blockIdx.y * 64;
    int tid = threadIdx.x;
    __shared__ __align__(16) u16 As[64*64];
    __shared__ __align__(16) u16 Bs[64*64];
    int wave = tid >> 6, lane = tid & 63;
    int wr = (wave >> 1) * 32, wc = (wave & 1) * 32;
    int q = lane >> 4, l16 = lane & 15;
    f32x4 acc[2][2] = {};
    const u16* ag = Abf + (size_t)n0*K3H;
    const u16* bg = Bbf + (size_t)o0*K3H;
    for (int k0 = 0; k0 < K3H; k0 += 64) {
        #pragma unroll
        for (int p = 0; p < 2; ++p) {
            int sl = p*256 + tid; int rr = sl >> 3, gi = sl & 7, g = gi ^ (rr & 7);
            gl_lds16(ag + (size_t)rr*K3H + k0 + g*8, As + sl*8);
            gl_lds16(bg + (size_t)rr*K3H + k0 + g*8, Bs + sl*8);
        }
        __syncthreads();
        #pragma unroll
        for (int ks = 0; ks < 2; ++ks) {
            int g = ks*4 + q;
            bf16x8 a0 = frag64(As, wr + l16, g);
            bf16x8 a1 = frag64(As, wr + 16 + l16, g);
            bf16x8 b0 = frag64(Bs, wc + l16, g);
            bf16x8 b1 = frag64(Bs, wc + 16 + l16, g);
            acc[0][0] = __builtin_amdgcn_mfma_f32_16x16x32_bf16(a0, b0, acc[0][0], 0,0,0);
            acc[0][1] = __builtin_amdgcn_mfma_f32_16x16x32_bf16(a0, b1, acc[0][1], 0,0,0);
            acc[1][0] = __builtin_amdgcn_mfma_f32_16x16x32_bf16(a1, b0, acc[1][0], 0,0,0);
            acc[1][1] = __builtin_amdgcn_mfma_f32_16x16x32_bf16(a1, b1, acc[1][1], 0,0,0);
        }
        __syncthreads();
    }
    #pragma unroll
    for (int rt = 0; rt < 2; ++rt) {
        #pragma unroll
        for (int ct = 0; ct < 2; ++ct) {
            int o = o0 + wc + ct*16 + l16;
            float bv = bias[o];
            #pragma unroll
            for (int r = 0; r < 4; ++r) {
                int m = n0 + wr + rt*16 + q*4 + r;
                Cbf[(size_t)m*OH + o] = f2bf(fmaxf(acc[rt][ct][r] + bv, 0.f));
            }
        }
    }
}

// ---------------------------------------------------------------------------
// G2: out = alpha * (h1 @ w2^T + vb2).  64x64 tile, BK=64.
// ---------------------------------------------------------------------------
__global__ __launch_bounds__(256) void k_mfma_gemm2(
    const u16* __restrict__ Abf, const u16* __restrict__ Bbf,
    const float* __restrict__ bias, const float* __restrict__ alpha,
    float* __restrict__ out)
{
    int o0 = blockIdx.x * 64;
    int n0 = blockIdx.y * 64;
    int tid = threadIdx.x;
    __shared__ __align__(16) u16 As[64*64];
    __shared__ __align__(16) u16 Bs[64*64];
    int wave = tid >> 6, lane = tid & 63;
    int wr = (wave >> 1) * 32, wc = (wave & 1) * 32;
    int q = lane >> 4, l16 = lane & 15;
    f32x4 acc[2][2] = {};
    const u16* ag = Abf + (size_t)n0*OH;
    const u16* bg = Bbf + (size_t)o0*OH;
    for (int k0 = 0; k0 < OH; k0 += 64) {
        #pragma unroll
        for (int p = 0; p < 2; ++p) {
            int sl = p*256 + tid; int rr = sl >> 3, gi = sl & 7, g = gi ^ (rr & 7);
            gl_lds16(ag + (size_t)rr*OH + k0 + g*8, As + sl*8);
            gl_lds16(bg + (size_t)rr*OH + k0 + g*8, Bs + sl*8);
        }
        __syncthreads();
        #pragma unroll
        for (int ks = 0; ks < 2; ++ks) {
            int g = ks*4 + q;
            bf16x8 a0 = frag64(As, wr + l16, g);
            bf16x8 a1 = frag64(As, wr + 16 + l16, g);
            bf16x8 b0 = frag64(Bs, wc + l16, g);
            bf16x8 b1 = frag64(Bs, wc + 16 + l16, g);
            acc[0][0] = __builtin_amdgcn_mfma_f32_16x16x32_bf16(a0, b0, acc[0][0], 0,0,0);
            acc[0][1] = __builtin_amdgcn_mfma_f32_16x16x32_bf16(a0, b1, acc[0][1], 0,0,0);
            acc[1][0] = __builtin_amdgcn_mfma_f32_16x16x32_bf16(a1, b0, acc[1][0], 0,0,0);
            acc[1][1] = __builtin_amdgcn_mfma_f32_16x16x32_bf16(a1, b1, acc[1][1], 0,0,0);
        }
        __syncthreads();
    }
    float al = alpha[0];
    #pragma unroll
    for (int rt = 0; rt < 2; ++rt) {
        #pragma unroll
        for (int ct = 0; ct < 2; ++ct) {
            int o = o0 + wc + ct*16 + l16;
            float bv = bias[o];
            #pragma unroll
            for (int r = 0; r < 4; ++r) {
                int m = n0 + wr + rt*16 + q*4 + r;
                out[(size_t)m*HH + o] = al * (acc[rt][ct][r] + bv);
            }
        }
    }
}

// ---------------------------------------------------------------------------
extern "C" void kernel_launch(void* const* d_in, const int* in_sizes, int n_in,
                              void* d_out, int out_size, void* d_ws, size_t ws_size,
                              hipStream_t stream) {
    const float* Hj    = (const float*)d_in[0];
    const float* Hi    = (const float*)d_in[1];
    const float* amask = (const float*)d_in[2];
    const float* pjw   = (const float*)d_in[3];
    const float* piw   = (const float*)d_in[4];
    const float* sw1   = (const float*)d_in[5];
    const float* sb1   = (const float*)d_in[6];
    const float* sw2   = (const float*)d_in[7];
    const float* sb2   = (const float*)d_in[8];
    const float* vw1   = (const float*)d_in[9];
    const float* vb1   = (const float*)d_in[10];
    const float* vw2   = (const float*)d_in[11];
    const float* vb2   = (const float*)d_in[12];
    const float* alpha = (const float*)d_in[13];
    float* out = (float*)d_out;
    (void)sb2; // softmax is shift-invariant; sb2 cancels

    u16* bfbase = (u16*)d_ws;
    u16* msginb = bfbase + MB_MSGIN;
    u16* h1b    = bfbase + MB_H1;
    u16* w1b    = bfbase + MB_W1;
    u16* w2b    = bfbase + MB_W2;
    u16* probsb = bfbase + MB_PROBS;
    u16* hitb   = bfbase + MB_HIT;
    u16* zjp    = bfbase + MB_ZJP;
    u16* zip    = bfbase + MB_ZIP;
    u16* wm     = bfbase + MB_WM;
    u16* wab    = bfbase + MB_WAB;
    u16* ab     = bfbase + MB_AB;

    k_wm<<<1, 256, 0, stream>>>(sw1, wm, wab);
    k_prep<<<PHT_END, 256, 0, stream>>>(Hj, Hi, pjw, piw, sb1, vw1, vw2, wab,
                                        w1b, w2b, zjp, zip, ab, msginb, hitb);
    k_pair_mfma<<<BB*SS/2, 256, 0, stream>>>(zjp, zip, ab, wm, sw2, amask, probsb);
    k_ctx_mfma<<<dim3(HH/64, SS/64, BB), 256, 0, stream>>>(probsb, hitb, msginb);
    k_mfma_gemm1<<<dim3(OH/64, BB*SS/64), 256, 0, stream>>>(msginb, w1b, vb1, h1b);
    k_mfma_gemm2<<<dim3(HH/64, BB*SS/64), 256, 0, stream>>>(h1b, w2b, vb2, alpha, out);
}